// Round 5
// baseline (568.731 us; speedup 1.0000x reference)
//
#include <hip/hip_runtime.h>
#include <hip/hip_bf16.h>
#include <math.h>

// Problem constants
#define Bb 4
#define Ss 4096
#define Dd 1024
#define Hh 16
#define Ff 256
#define HDd 64
#define Mm (Bb*Ss)          // 16384 rows

typedef unsigned int u32;
typedef unsigned short u16;

typedef __attribute__((ext_vector_type(8))) short bf16x8;   // 8 bf16 = 4 VGPRs
typedef __attribute__((ext_vector_type(4))) float f32x4;

// ---- bf16 helpers ----
__device__ __forceinline__ float bflo(u32 u){ union{u32 i; float f;} c; c.i = u << 16; return c.f; }
__device__ __forceinline__ float bfhi(u32 u){ union{u32 i; float f;} c; c.i = u & 0xffff0000u; return c.f; }
__device__ __forceinline__ u16 f2b(float f){
  union{float f; u32 i;} c; c.f = f;
  u32 x = c.i;
  return (u16)((x + 0x7fffu + ((x >> 16) & 1u)) >> 16);   // RNE
}
// packed f32x2 -> bf16x2 (RNE, compiler emits v_cvt_pk_bf16_f32; same bits as f2b)
__device__ __forceinline__ u32 pk2(float lo, float hi){
  union { __hip_bfloat162 h; u32 u; } c;
  c.h = __float22bfloat162_rn(make_float2(lo, hi));
  return c.u;
}
// fast softplus for the MFMA paths (v_exp/v_log native; err << bf16 noise)
__device__ __forceinline__ float sfast(float x){
  return fmaxf(x, 0.f) + __logf(1.f + __expf(-fabsf(x)));
}
// async global->LDS, 16B per lane: LDS dest = wave-uniform base + lane*16
__device__ __forceinline__ void gload_lds16(const u16* g, u16* l){
  __builtin_amdgcn_global_load_lds(
      (const __attribute__((address_space(1))) void*)g,
      (__attribute__((address_space(3))) void*)l, 16, 0, 0);
}

// ============================================================
// f32 -> bf16 elementwise (8 elems/thread, vectorized)
// ============================================================
__global__ void cvt_bf16(const float* __restrict__ in, u16* __restrict__ out, int n)
{
  int i = (blockIdx.x * 256 + threadIdx.x) * 8;
  if (i >= n) return;
  float4 a = *reinterpret_cast<const float4*>(in + i);
  float4 b = *reinterpret_cast<const float4*>(in + i + 4);
  *reinterpret_cast<uint4*>(out + i) =
      make_uint4(pk2(a.x, a.y), pk2(a.z, a.w), pk2(b.x, b.y), pk2(b.z, b.w));
}

// ============================================================
// zero-fill (ws is re-poisoned 0xAA each call)
// ============================================================
__global__ void zero_f32(float* __restrict__ p, int n)
{
  int i = blockIdx.x * 256 + threadIdx.x;
  if (i < n) p[i] = 0.f;
}

// ============================================================
// MFMA GEMM: C[M,N] = A[M,K](bf16) * W[N,K]^T(bf16) + bias
// OT = u16 (bf16 store) or float (f32 store).
// BROW: bias indexed by row m (for the V^T gemm) instead of col n.
// 128x128 tile, BK=32, 4 waves (2x2 of 64x64).
// Staging via global_load_lds width=16 (m97 structure, linear [128][32] LDS).
// Verified frag layouts (m89/m91/m120): A[m=lane&15][k=quad*8+j],
// B[k=quad*8+j][n=lane&15], D[row=quad*4+r][col=lane&15].
// ============================================================
template<typename OT, bool BROW>
__global__ __launch_bounds__(256, 2) void mfma_gemm_bt(
    const u16* __restrict__ A, const u16* __restrict__ W,
    const float* __restrict__ bias, OT* __restrict__ C,
    int M, int N, int K)
{
  __shared__ __align__(16) u16 As[128 * 32];   // 8KB, linear (gload_lds needs it)
  __shared__ __align__(16) u16 Bs[128 * 32];   // 8KB

  const int tid = threadIdx.x;
  const int wave = tid >> 6, lane = tid & 63;
  const int quad = lane >> 4, lm = lane & 15;
  const int wm = (wave >> 1) * 64, wn = (wave & 1) * 64;
  const int m0 = blockIdx.x * 128, n0 = blockIdx.y * 128;

  f32x4 acc[4][4] = {};   // zero-init

  for (int k0 = 0; k0 < K; k0 += 32) {
#pragma unroll
    for (int j = 0; j < 2; j++) {
      const int c = wave * 128 + j * 64 + lane;     // chunk 0..511
      const int r = c >> 2, cg = c & 3;
      u16* ldsA = &As[(wave * 128 + j * 64) * 8];   // wave-uniform base
      u16* ldsB = &Bs[(wave * 128 + j * 64) * 8];
      gload_lds16(A + (size_t)(m0 + r) * K + k0 + cg * 8, ldsA);
      gload_lds16(W + (size_t)(n0 + r) * K + k0 + cg * 8, ldsB);
    }
    __syncthreads();   // implicit vmcnt(0) drain completes the LDS writes

    bf16x8 af[4], bf[4];
#pragma unroll
    for (int mi = 0; mi < 4; mi++)
      af[mi] = *reinterpret_cast<const bf16x8*>(&As[(wm + mi * 16 + lm) * 32 + quad * 8]);
#pragma unroll
    for (int ni = 0; ni < 4; ni++)
      bf[ni] = *reinterpret_cast<const bf16x8*>(&Bs[(wn + ni * 16 + lm) * 32 + quad * 8]);
#pragma unroll
    for (int mi = 0; mi < 4; mi++)
#pragma unroll
      for (int ni = 0; ni < 4; ni++)
        acc[mi][ni] = __builtin_amdgcn_mfma_f32_16x16x32_bf16(af[mi], bf[ni], acc[mi][ni], 0, 0, 0);
    __syncthreads();
  }

  // epilogue: lane l, reg r -> C[m0+wm+mi*16+quad*4+r][n0+wn+ni*16+lm]
#pragma unroll
  for (int mi = 0; mi < 4; mi++)
#pragma unroll
    for (int ni = 0; ni < 4; ni++) {
      const int n = n0 + wn + ni * 16 + lm;
      const float bvn = BROW ? 0.f : bias[n];
#pragma unroll
      for (int r = 0; r < 4; r++) {
        const int m = m0 + wm + mi * 16 + quad * 4 + r;
        const float val = acc[mi][ni][r] + (BROW ? bias[m] : bvn);
        if constexpr (sizeof(OT) == 2) ((u16*)C)[(size_t)m * N + n] = f2b(val);
        else                           ((float*)C)[(size_t)m * N + n] = val;
      }
    }
}

// ============================================================
// rf [H][HD][F] f32 -> rft [H][F][HD] f32 (contiguous wave-uniform rows)
// ============================================================
__global__ void rf_transpose(const float* __restrict__ rf, float* __restrict__ rft)
{
  const int h = blockIdx.x, d = blockIdx.y, f = threadIdx.x;
  rft[((size_t)h * Ff + f) * HDd + d] = rf[((size_t)(h * HDd + d)) * Ff + f];
}

// ============================================================
// Fused kv/ksum via MFMA — round-5 restructure:
//  * rf B-operand in REGISTERS (drops 32KB RF LDS; attn_fused-proven pattern)
//  * K/Vt staged via global_load_lds w16 with PRE-SWIZZLED SOURCE (rule 21:
//    linear LDS dest, source col c = cs^(r&7); XOR is an involution so the
//    existing swizzled reads recover c = ks*4+quad unchanged)
//  * double-buffered KS/VS + counted vmcnt(4) + raw s_barrier: next chunk's
//    loads stay in flight across the barrier (T3/T4 minimum pipeline;
//    __syncthreads would drain vmcnt(0) and serialize load/compute)
// LDS 64KB -> 2 blocks/CU.
// ============================================================
#define NSPLIT 8
#define SCHUNKS (Ss / NSPLIT / 64)   // 8 chunks of 64 rows

__global__ __launch_bounds__(256, 2) void kv_fused(
    const u16* __restrict__ Km, const u16* __restrict__ Vt,
    const float* __restrict__ rft, float* __restrict__ kv, float* __restrict__ ksum)
{
  __shared__ __align__(16) u16 KSd[2][64 * 64];   // 2x8KB  K chunk [s][d] swizzled
  __shared__ __align__(16) u16 VSd[2][64 * 64];   // 2x8KB  Vt chunk [d][s] swizzled
  __shared__ __align__(16) u16 PT[4][64 * 64];    // 32KB per-wave P^T [f][s] swizzled

  const int bh = blockIdx.x;
  const int b = bh >> 4, h = bh & 15;
  const int s0 = blockIdx.y * (Ss / NSPLIT);
  const int tid = threadIdx.x;
  const int wave = tid >> 6, lane = tid & 63;
  const int quad = lane >> 4, lm = lane & 15;
  const int F0 = wave * 64;

  // rf fragments in regs (stage-1 B operand): rft[h][F0+ni*16+lm][ks*32+quad*8..+8]
  bf16x8 bfr[4][2];
  {
    const float* rh = rft + (size_t)h * Ff * HDd;
#pragma unroll
    for (int ni = 0; ni < 4; ni++) {
      const float* rrow = rh + (size_t)(F0 + ni * 16 + lm) * HDd;
#pragma unroll
      for (int ks = 0; ks < 2; ks++) {
        float4 a = *reinterpret_cast<const float4*>(rrow + ks * 32 + quad * 8);
        float4 e = *reinterpret_cast<const float4*>(rrow + ks * 32 + quad * 8 + 4);
        union { u32 w[4]; bf16x8 v; } u;
        u.w[0] = pk2(a.x, a.y); u.w[1] = pk2(a.z, a.w);
        u.w[2] = pk2(e.x, e.y); u.w[3] = pk2(e.z, e.w);
        bfr[ni][ks] = u.v;
      }
    }
  }

  // staging geometry: slot j in [0,512): LDS byte j*16; r=j>>3, cs=j&7,
  // source col c = cs ^ (r&7). Wave w covers slots w*64+lane and +256.
  const int j0 = wave * 64 + lane, j1 = j0 + 256;
  const int r0 = j0 >> 3, c0 = (j0 & 7) ^ (r0 & 7);
  const int r1 = j1 >> 3, c1 = (j1 & 7) ^ (r1 & 7);

  auto KV_STAGE = [&](int buf, int ch) {
    const int sc = s0 + ch * 64;
    gload_lds16(Km + (size_t)(b * Ss + sc + r0) * Dd + h * 64 + c0 * 8, &KSd[buf][(wave * 64) * 8]);
    gload_lds16(Km + (size_t)(b * Ss + sc + r1) * Dd + h * 64 + c1 * 8, &KSd[buf][(wave * 64 + 256) * 8]);
    gload_lds16(Vt + (size_t)(h * 64 + r0) * Mm + b * Ss + sc + c0 * 8, &VSd[buf][(wave * 64) * 8]);
    gload_lds16(Vt + (size_t)(h * 64 + r1) * Mm + b * Ss + sc + c1 * 8, &VSd[buf][(wave * 64 + 256) * 8]);
  };

  f32x4 kvacc[4][4] = {};
  float kss[4] = {0.f, 0.f, 0.f, 0.f};

  KV_STAGE(0, 0);

#pragma unroll
  for (int ch = 0; ch < SCHUNKS; ch++) {
    const int cur = ch & 1;
    if (ch + 1 < SCHUNKS) {
      KV_STAGE(cur ^ 1, ch + 1);                       // prefetch next (4 loads in flight)
      asm volatile("s_waitcnt vmcnt(4)" ::: "memory"); // wait only current chunk's 4
    } else {
      asm volatile("s_waitcnt vmcnt(0)" ::: "memory");
    }
    __builtin_amdgcn_s_barrier();                      // all waves' current-buf writes visible
    __builtin_amdgcn_sched_barrier(0);

    const u16* KSc = &KSd[cur][0];
    const u16* VSc = &VSd[cur][0];

    // stage 1: P[s 0..63][f F0..F0+63] = K @ rf^T (B from regs; 2 k-steps)
    f32x4 p[4][4] = {};
#pragma unroll
    for (int ks2 = 0; ks2 < 2; ks2++) {
      bf16x8 af[4];
#pragma unroll
      for (int mi = 0; mi < 4; mi++) {
        int row = mi * 16 + lm;                        // s row
        af[mi] = *reinterpret_cast<const bf16x8*>(
            (const char*)KSc + row * 128 + (((ks2 * 4 + quad) ^ (row & 7)) * 16));
      }
#pragma unroll
      for (int mi = 0; mi < 4; mi++)
#pragma unroll
        for (int ni = 0; ni < 4; ni++)
          p[mi][ni] = __builtin_amdgcn_mfma_f32_16x16x32_bf16(af[mi], bfr[ni][ks2], p[mi][ni], 0, 0, 0);
    }

    // softplus + ksum partials + write P^T bf16 into this wave's PT slice
#pragma unroll
    for (int mi = 0; mi < 4; mi++)
#pragma unroll
      for (int ni = 0; ni < 4; ni++) {
        float v0 = sfast(p[mi][ni][0]);
        float v1 = sfast(p[mi][ni][1]);
        float v2 = sfast(p[mi][ni][2]);
        float v3 = sfast(p[mi][ni][3]);
        kss[ni] += (v0 + v1) + (v2 + v3);
        int row = ni * 16 + lm;                        // f row; s cols = mi*16+quad*4+rr
        int off = (row * 128 + mi * 32 + quad * 8) ^ ((row & 7) << 4);
        *reinterpret_cast<uint2*>((char*)&PT[wave][0] + off) =
            make_uint2(pk2(v0, v1), pk2(v2, v3));
      }

    // stage 2: kv[f][d] += P^T @ Vt (own PT + shared VSc; 2 k-steps)
#pragma unroll
    for (int ks2 = 0; ks2 < 2; ks2++) {
      bf16x8 a2[4], b2[4];
#pragma unroll
      for (int mi = 0; mi < 4; mi++) {
        int row = mi * 16 + lm;                        // f row
        a2[mi] = *reinterpret_cast<const bf16x8*>(
            (char*)&PT[wave][0] + row * 128 + (((ks2 * 4 + quad) ^ (row & 7)) * 16));
      }
#pragma unroll
      for (int ni = 0; ni < 4; ni++) {
        int row = ni * 16 + lm;                        // d row
        b2[ni] = *reinterpret_cast<const bf16x8*>(
            (const char*)VSc + row * 128 + (((ks2 * 4 + quad) ^ (row & 7)) * 16));
      }
#pragma unroll
      for (int mi = 0; mi < 4; mi++)
#pragma unroll
        for (int ni = 0; ni < 4; ni++)
          kvacc[mi][ni] = __builtin_amdgcn_mfma_f32_16x16x32_bf16(a2[mi], b2[ni], kvacc[mi][ni], 0, 0, 0);
    }

    __builtin_amdgcn_sched_barrier(0);
    __builtin_amdgcn_s_barrier();   // all waves done with cur before next STAGE overwrites it
  }

  // epilogue: f32 atomics into kv[bh][f][d] and ksum[bh][f]
  float* kvp = kv + (size_t)bh * Ff * HDd;
#pragma unroll
  for (int mi = 0; mi < 4; mi++)
#pragma unroll
    for (int ni = 0; ni < 4; ni++)
#pragma unroll
      for (int rr = 0; rr < 4; rr++) {
        int f = F0 + mi * 16 + quad * 4 + rr;
        int d = ni * 16 + lm;
        atomicAdd(kvp + (size_t)f * HDd + d, kvacc[mi][ni][rr]);
      }
#pragma unroll
  for (int ni = 0; ni < 4; ni++) {
    float v = kss[ni];
    v += __shfl_xor(v, 16, 64);
    v += __shfl_xor(v, 32, 64);
    if (quad == 0) atomicAdd(ksum + (size_t)bh * Ff + F0 + ni * 16 + lm, v);
  }
}

// ============================================================
// kv f32 [bh][f=256][d=64] -> kvT bf16 [bh][d=64][f=256]
// ============================================================
__global__ void kvt_cvt(const float* __restrict__ kv, u16* __restrict__ kvtb)
{
  const int bh = blockIdx.x;
  const int d = threadIdx.x & 63, fg = threadIdx.x >> 6;
  const float* src = kv + (size_t)bh * Ff * HDd + d;
  u32* dst = reinterpret_cast<u32*>(kvtb + (size_t)bh * HDd * Ff + (size_t)d * Ff + fg * 64);
#pragma unroll
  for (int j = 0; j < 32; j++) {
    float v0 = src[(size_t)(fg * 64 + 2 * j) * HDd];
    float v1 = src[(size_t)(fg * 64 + 2 * j + 1) * HDd];
    dst[j] = pk2(v0, v1);
  }
}

// ============================================================
// Fused attention via MFMA (round-4, verified: ASPLIT=16, (256,2)).
// ============================================================
#define ASPLIT 16
#define ACHUNKS (Ss / ASPLIT / 64)   // 4 chunks of 64 rows

__global__ __launch_bounds__(256, 2) void attn_fused(
    const u16* __restrict__ Qm, const float* __restrict__ rft,
    const u16* __restrict__ kvtb, const float* __restrict__ ksum,
    u16* __restrict__ attnb)
{
  __shared__ __align__(16) u16 P4[4][64 * 64];    // 32KB [fb][s][f'] swizzled
  __shared__ __align__(16) float den4[64][4];     // [s][wave] partial denominators

  const int bh = blockIdx.x;
  const int b = bh >> 4, h = bh & 15;
  const int s0 = blockIdx.y * (Ss / ASPLIT);
  const int tid = threadIdx.x;
  const int wave = tid >> 6, lane = tid & 63;
  const int quad = lane >> 4, lm = lane & 15;
  const int F0 = wave * 64;

  // rf fragments (stage-1 B operand): rft[h][F0+ni*16+lm][ks*32+quad*8 ..+8]
  bf16x8 bfr[4][2];
  {
    const float* rh = rft + (size_t)h * Ff * HDd;
#pragma unroll
    for (int ni = 0; ni < 4; ni++) {
      const float* rrow = rh + (size_t)(F0 + ni * 16 + lm) * HDd;
#pragma unroll
      for (int ks = 0; ks < 2; ks++) {
        float4 a = *reinterpret_cast<const float4*>(rrow + ks * 32 + quad * 8);
        float4 e = *reinterpret_cast<const float4*>(rrow + ks * 32 + quad * 8 + 4);
        union { u32 w[4]; bf16x8 v; } u;
        u.w[0] = pk2(a.x, a.y); u.w[1] = pk2(a.z, a.w);
        u.w[2] = pk2(e.x, e.y); u.w[3] = pk2(e.z, e.w);
        bfr[ni][ks] = u.v;
      }
    }
  }
  // kvT fragments (stage-2 B operand): kvtb[bh][wave*16+lm][fb*64+k2*32+quad*8 ..+8]
  bf16x8 b2r[4][2];
  {
    const u16* kb = kvtb + (size_t)bh * HDd * Ff + (size_t)(wave * 16 + lm) * Ff;
#pragma unroll
    for (int fb = 0; fb < 4; fb++)
#pragma unroll
      for (int k2 = 0; k2 < 2; k2++)
        b2r[fb][k2] = *reinterpret_cast<const bf16x8*>(kb + fb * 64 + k2 * 32 + quad * 8);
  }
  // ksum per lane (f = F0 + ni*16 + lm)
  float ksv[4];
#pragma unroll
  for (int ni = 0; ni < 4; ni++)
    ksv[ni] = ksum[(size_t)bh * Ff + F0 + ni * 16 + lm];

  for (int ch = 0; ch < ACHUNKS; ch++) {
    const int sc0 = s0 + ch * 64;

    // stage 1: Q fragments direct from global (read-once), MFMA
    bf16x8 af[4][2];
#pragma unroll
    for (int mi = 0; mi < 4; mi++) {
      const u16* qrow = Qm + (size_t)(b * Ss + sc0 + mi * 16 + lm) * Dd + h * 64;
#pragma unroll
      for (int ks = 0; ks < 2; ks++)
        af[mi][ks] = *reinterpret_cast<const bf16x8*>(qrow + ks * 32 + quad * 8);
    }
    f32x4 p[4][4] = {};
#pragma unroll
    for (int ks = 0; ks < 2; ks++)
#pragma unroll
      for (int mi = 0; mi < 4; mi++)
#pragma unroll
        for (int ni = 0; ni < 4; ni++)
          p[mi][ni] = __builtin_amdgcn_mfma_f32_16x16x32_bf16(af[mi][ks], bfr[ni][ks], p[mi][ni], 0, 0, 0);

    // softplus + cvt_pk round + den partials (from ROUNDED qp) + lane-pair pack
#pragma unroll
    for (int mi = 0; mi < 4; mi++) {
      const int sbase = mi * 16 + quad * 4;
      float dd[4] = {0.f, 0.f, 0.f, 0.f};
#pragma unroll
      for (int ni = 0; ni < 4; ni++) {
        u32 pk01 = pk2(sfast(p[mi][ni][0]), sfast(p[mi][ni][1]));
        u32 pk23 = pk2(sfast(p[mi][ni][2]), sfast(p[mi][ni][3]));
        dd[0] += bflo(pk01) * ksv[ni];
        dd[1] += bfhi(pk01) * ksv[ni];
        dd[2] += bflo(pk23) * ksv[ni];
        dd[3] += bfhi(pk23) * ksv[ni];
        u32 ob01 = (u32)__shfl_xor((int)pk01, 1, 64);
        u32 ob23 = (u32)__shfl_xor((int)pk23, 1, 64);
        const int odd = lm & 1;
        // even lane writes rows sbase+0,1 (r=0,1 pairs); odd lane rows sbase+2,3
        u32 w_a = odd ? ((ob23 & 0xffffu) | (pk23 << 16))
                      : ((pk01 & 0xffffu) | (ob01 << 16));
        u32 w_b = odd ? ((ob23 >> 16)     | (pk23 & 0xffff0000u))
                      : ((pk01 >> 16)     | (ob01 & 0xffff0000u));
        const int row_a = sbase + (odd ? 2 : 0);
        const int row_b = sbase + (odd ? 3 : 1);
        const int fpb = ni * 16 + (lm & ~1);
        const int cc = fpb >> 3;
        const int bib = (fpb & 7) * 2;
        *reinterpret_cast<u32*>((char*)&P4[wave][0] + row_a * 128 + ((cc ^ (row_a & 7)) << 4) + bib) = w_a;
        *reinterpret_cast<u32*>((char*)&P4[wave][0] + row_b * 128 + ((cc ^ (row_b & 7)) << 4) + bib) = w_b;
      }
      // reduce den partials over lm (16-lane groups), write per-wave partial
#pragma unroll
      for (int r = 0; r < 4; r++) {
        float v = dd[r];
        v += __shfl_xor(v, 1, 64);
        v += __shfl_xor(v, 2, 64);
        v += __shfl_xor(v, 4, 64);
        v += __shfl_xor(v, 8, 64);
        if (lm == 0) den4[sbase + r][wave] = v;
      }
    }
    __syncthreads();   // P4 + den4 complete

    // stage 2: attn[s][d] = P @ kvT, waves split by 16-wide d-slices
    f32x4 acc2[4] = {};
#pragma unroll
    for (int fb = 0; fb < 4; fb++)
#pragma unroll
      for (int k2 = 0; k2 < 2; k2++) {
        bf16x8 af2[4];
#pragma unroll
        for (int mi = 0; mi < 4; mi++) {
          int row = mi * 16 + lm;                  // s row
          af2[mi] = *reinterpret_cast<const bf16x8*>(
              (char*)&P4[fb][0] + row * 128 + (((k2 * 4 + quad) ^ (row & 7)) << 4));
        }
#pragma unroll
        for (int mi = 0; mi < 4; mi++)
          acc2[mi] = __builtin_amdgcn_mfma_f32_16x16x32_bf16(af2[mi], b2r[fb][k2], acc2[mi], 0, 0, 0);
      }

    // divide by den, bf16 store: out[s = mi*16+quad*4+r][d = wave*16+lm]
#pragma unroll
    for (int mi = 0; mi < 4; mi++) {
#pragma unroll
      for (int r = 0; r < 4; r++) {
        const int s = mi * 16 + quad * 4 + r;
        float4 dv = *reinterpret_cast<const float4*>(&den4[s][0]);
        const float inv = 1.f / ((dv.x + dv.y) + (dv.z + dv.w) + 1e-8f);
        attnb[(size_t)(b * Ss + sc0 + s) * Dd + h * 64 + wave * 16 + lm] =
            f2b(acc2[mi][r] * inv);
      }
    }
    __syncthreads();   // before next chunk overwrites P4/den4
  }
}

// ============================================================
extern "C" void kernel_launch(void* const* d_in, const int* in_sizes, int n_in,
                              void* d_out, int out_size, void* d_ws, size_t ws_size,
                              hipStream_t stream)
{
  const float* x  = (const float*)d_in[0];
  const float* Wq = (const float*)d_in[1];
  const float* bq = (const float*)d_in[2];
  const float* Wk = (const float*)d_in[3];
  const float* bk = (const float*)d_in[4];
  const float* Wv = (const float*)d_in[5];
  const float* bv = (const float*)d_in[6];
  const float* Wo = (const float*)d_in[7];
  const float* bo = (const float*)d_in[8];
  const float* rf = (const float*)d_in[9];

  // workspace (~147 MB). attn-bf16 ALIASES xb (dead after V^T GEMM);
  // kvT-bf16 ALIASES wqb (dead after Q GEMM).
  char* w = (char*)d_ws;
  u16* xb = (u16*)w;        w += (size_t)Mm * Dd * 2;               // 33.5 MB (also attn-bf16)
  u16* q  = (u16*)w;        w += (size_t)Mm * Dd * 2;               // 33.5 MB
  u16* k  = (u16*)w;        w += (size_t)Mm * Dd * 2;               // 33.5 MB
  u16* vt = (u16*)w;        w += (size_t)Mm * Dd * 2;               // 33.5 MB  V^T [1024][16384]
  u16* wqb = (u16*)w;       w += (size_t)Dd * Dd * 2;               // 2 MB (also kvT bf16)
  u16* wkb = (u16*)w;       w += (size_t)Dd * Dd * 2;
  u16* wvb = (u16*)w;       w += (size_t)Dd * Dd * 2;
  u16* wob = (u16*)w;       w += (size_t)Dd * Dd * 2;
  float* kv = (float*)w;    w += (size_t)(Bb * Hh) * Ff * HDd * 4;  // 4.19 MB
  float* ks = (float*)w;    w += (size_t)(Bb * Hh) * Ff * 4;        // 64 KB
  float* rft = (float*)w;   w += (size_t)Hh * Ff * HDd * 4;         // 1.05 MB
  u16* kvtb = wqb;          // 2 MB alias: kvT bf16 [bh][d][f]

  // f32 -> bf16 conversions
  cvt_bf16<<<(Mm * Dd / 8 + 255) / 256, 256, 0, stream>>>(x, xb, Mm * Dd);
  cvt_bf16<<<(Dd * Dd / 8 + 255) / 256, 256, 0, stream>>>(Wq, wqb, Dd * Dd);
  cvt_bf16<<<(Dd * Dd / 8 + 255) / 256, 256, 0, stream>>>(Wk, wkb, Dd * Dd);
  cvt_bf16<<<(Dd * Dd / 8 + 255) / 256, 256, 0, stream>>>(Wv, wvb, Dd * Dd);
  cvt_bf16<<<(Dd * Dd / 8 + 255) / 256, 256, 0, stream>>>(Wo, wob, Dd * Dd);

  const int nz = (Bb * Hh) * Ff * HDd + (Bb * Hh) * Ff;
  zero_f32<<<(nz + 255) / 256, 256, 0, stream>>>(kv, nz);
  rf_transpose<<<dim3(Hh, HDd), 256, 0, stream>>>(rf, rft);

  const dim3 gg(Mm / 128, Dd / 128);
  mfma_gemm_bt<u16, false><<<gg, 256, 0, stream>>>(xb, wqb, bq, q, Mm, Dd, Dd);
  mfma_gemm_bt<u16, false><<<gg, 256, 0, stream>>>(xb, wkb, bk, k, Mm, Dd, Dd);
  // V^T directly: C[d][m] = sum_k Wv[d][k] x[m][k] + bv[d]  (bias per-row)
  const dim3 gv(Dd / 128, Mm / 128);
  mfma_gemm_bt<u16, true><<<gv, 256, 0, stream>>>(wvb, xb, bv, vt, Dd, Mm, Dd);

  // fused MFMA kv/ksum
  kv_fused<<<dim3(Bb * Hh, NSPLIT), 256, 0, stream>>>(k, vt, rft, kv, ks);

  // kv -> kvT bf16 (into dead wqb region)
  kvt_cvt<<<Bb * Hh, 256, 0, stream>>>(kv, kvtb);

  // fused MFMA attention (writes bf16 into dead xb region)
  attn_fused<<<dim3(Bb * Hh, ASPLIT), 256, 0, stream>>>(q, rft, kvtb, ks, xb);

  // final projection: f32 output
  mfma_gemm_bt<float, false><<<gg, 256, 0, stream>>>(xb, wob, bo, (float*)d_out, Mm, Dd, Dd);
}

// Round 6
// 505.802 us; speedup vs baseline: 1.1244x; 1.1244x over previous
//
#include <hip/hip_runtime.h>
#include <hip/hip_bf16.h>
#include <math.h>

// Problem constants
#define Bb 4
#define Ss 4096
#define Dd 1024
#define Hh 16
#define Ff 256
#define HDd 64
#define Mm (Bb*Ss)          // 16384 rows

typedef unsigned int u32;
typedef unsigned short u16;

typedef __attribute__((ext_vector_type(8))) short bf16x8;   // 8 bf16 = 4 VGPRs
typedef __attribute__((ext_vector_type(4))) float f32x4;

// ---- bf16 helpers ----
__device__ __forceinline__ float bflo(u32 u){ union{u32 i; float f;} c; c.i = u << 16; return c.f; }
__device__ __forceinline__ float bfhi(u32 u){ union{u32 i; float f;} c; c.i = u & 0xffff0000u; return c.f; }
__device__ __forceinline__ u16 f2b(float f){
  union{float f; u32 i;} c; c.f = f;
  u32 x = c.i;
  return (u16)((x + 0x7fffu + ((x >> 16) & 1u)) >> 16);   // RNE
}
// packed f32x2 -> bf16x2 (RNE, compiler emits v_cvt_pk_bf16_f32; same bits as f2b)
__device__ __forceinline__ u32 pk2(float lo, float hi){
  union { __hip_bfloat162 h; u32 u; } c;
  c.h = __float22bfloat162_rn(make_float2(lo, hi));
  return c.u;
}
// fast softplus for the MFMA paths (v_exp/v_log native; err << bf16 noise)
__device__ __forceinline__ float sfast(float x){
  return fmaxf(x, 0.f) + __logf(1.f + __expf(-fabsf(x)));
}
// async global->LDS, 16B per lane: LDS dest = wave-uniform base + lane*16
__device__ __forceinline__ void gload_lds16(const u16* g, u16* l){
  __builtin_amdgcn_global_load_lds(
      (const __attribute__((address_space(1))) void*)g,
      (__attribute__((address_space(3))) void*)l, 16, 0, 0);
}

// ============================================================
// f32 -> bf16 elementwise (8 elems/thread, vectorized)
// ============================================================
__global__ void cvt_bf16(const float* __restrict__ in, u16* __restrict__ out, int n)
{
  int i = (blockIdx.x * 256 + threadIdx.x) * 8;
  if (i >= n) return;
  float4 a = *reinterpret_cast<const float4*>(in + i);
  float4 b = *reinterpret_cast<const float4*>(in + i + 4);
  *reinterpret_cast<uint4*>(out + i) =
      make_uint4(pk2(a.x, a.y), pk2(a.z, a.w), pk2(b.x, b.y), pk2(b.z, b.w));
}

// ============================================================
// zero-fill (ws is re-poisoned 0xAA each call)
// ============================================================
__global__ void zero_f32(float* __restrict__ p, int n)
{
  int i = blockIdx.x * 256 + threadIdx.x;
  if (i < n) p[i] = 0.f;
}

// ============================================================
// MFMA GEMM: C[M,N] = A[M,K](bf16) * W[N,K]^T(bf16) + bias
// OT = u16 (bf16 store) or float (f32 store).
// BROW: bias indexed by row m (for the V^T gemm) instead of col n.
// 128x128 tile, BK=32, 4 waves (2x2 of 64x64).
// Staging via global_load_lds width=16 (m97 structure, linear [128][32] LDS).
// Verified frag layouts (m89/m91/m120): A[m=lane&15][k=quad*8+j],
// B[k=quad*8+j][n=lane&15], D[row=quad*4+r][col=lane&15].
// ============================================================
template<typename OT, bool BROW>
__global__ __launch_bounds__(256, 2) void mfma_gemm_bt(
    const u16* __restrict__ A, const u16* __restrict__ W,
    const float* __restrict__ bias, OT* __restrict__ C,
    int M, int N, int K)
{
  __shared__ __align__(16) u16 As[128 * 32];   // 8KB, linear (gload_lds needs it)
  __shared__ __align__(16) u16 Bs[128 * 32];   // 8KB

  const int tid = threadIdx.x;
  const int wave = tid >> 6, lane = tid & 63;
  const int quad = lane >> 4, lm = lane & 15;
  const int wm = (wave >> 1) * 64, wn = (wave & 1) * 64;
  const int m0 = blockIdx.x * 128, n0 = blockIdx.y * 128;

  f32x4 acc[4][4] = {};   // zero-init

  for (int k0 = 0; k0 < K; k0 += 32) {
#pragma unroll
    for (int j = 0; j < 2; j++) {
      const int c = wave * 128 + j * 64 + lane;     // chunk 0..511
      const int r = c >> 2, cg = c & 3;
      u16* ldsA = &As[(wave * 128 + j * 64) * 8];   // wave-uniform base
      u16* ldsB = &Bs[(wave * 128 + j * 64) * 8];
      gload_lds16(A + (size_t)(m0 + r) * K + k0 + cg * 8, ldsA);
      gload_lds16(W + (size_t)(n0 + r) * K + k0 + cg * 8, ldsB);
    }
    __syncthreads();   // implicit vmcnt(0) drain completes the LDS writes

    bf16x8 af[4], bf[4];
#pragma unroll
    for (int mi = 0; mi < 4; mi++)
      af[mi] = *reinterpret_cast<const bf16x8*>(&As[(wm + mi * 16 + lm) * 32 + quad * 8]);
#pragma unroll
    for (int ni = 0; ni < 4; ni++)
      bf[ni] = *reinterpret_cast<const bf16x8*>(&Bs[(wn + ni * 16 + lm) * 32 + quad * 8]);
#pragma unroll
    for (int mi = 0; mi < 4; mi++)
#pragma unroll
      for (int ni = 0; ni < 4; ni++)
        acc[mi][ni] = __builtin_amdgcn_mfma_f32_16x16x32_bf16(af[mi], bf[ni], acc[mi][ni], 0, 0, 0);
    __syncthreads();
  }

  // epilogue: lane l, reg r -> C[m0+wm+mi*16+quad*4+r][n0+wn+ni*16+lm]
#pragma unroll
  for (int mi = 0; mi < 4; mi++)
#pragma unroll
    for (int ni = 0; ni < 4; ni++) {
      const int n = n0 + wn + ni * 16 + lm;
      const float bvn = BROW ? 0.f : bias[n];
#pragma unroll
      for (int r = 0; r < 4; r++) {
        const int m = m0 + wm + mi * 16 + quad * 4 + r;
        const float val = acc[mi][ni][r] + (BROW ? bias[m] : bvn);
        if constexpr (sizeof(OT) == 2) ((u16*)C)[(size_t)m * N + n] = f2b(val);
        else                           ((float*)C)[(size_t)m * N + n] = val;
      }
    }
}

// ============================================================
// rf [H][HD][F] f32 -> rft [H][F][HD] f32 (contiguous wave-uniform rows)
// ============================================================
__global__ void rf_transpose(const float* __restrict__ rf, float* __restrict__ rft)
{
  const int h = blockIdx.x, d = blockIdx.y, f = threadIdx.x;
  rft[((size_t)h * Ff + f) * HDd + d] = rf[((size_t)(h * HDd + d)) * Ff + f];
}

// ============================================================
// Fused kv/ksum via MFMA — round-6 anti-spill restructure:
//  * rf B-operand in regs (kept from r5)
//  * gload_lds w16 staging with pre-swizzled SOURCE (kept from r5; removes
//    VALU staging)
//  * SINGLE buffer + __syncthreads (dbuf dropped: it cost 64KB LDS + live regs)
//  * per-mi stage-1: pmi[4] (16 VGPR) instead of p[4][4] (64 VGPR). r5's
//    spill (FETCH 41->109MB, WRITE 48->183MB) came from ~190 live regs @128
//    alloc + full chunk-loop unroll.
//  * #pragma unroll 1 on chunk loop (r5's unroll ballooned live ranges)
//  * LDS 48KB -> 3 blocks/CU; NSPLIT 16 (1024 blocks) to use the occupancy
// ============================================================
#define NSPLIT 16
#define SCHUNKS (Ss / NSPLIT / 64)   // 4 chunks of 64 rows

__global__ __launch_bounds__(256, 2) void kv_fused(
    const u16* __restrict__ Km, const u16* __restrict__ Vt,
    const float* __restrict__ rft, float* __restrict__ kv, float* __restrict__ ksum)
{
  __shared__ __align__(16) u16 KS[64 * 64];       // 8KB  K chunk [s][d] swizzled
  __shared__ __align__(16) u16 VS[64 * 64];       // 8KB  Vt chunk [d][s] swizzled
  __shared__ __align__(16) u16 PT[4][64 * 64];    // 32KB per-wave P^T [f][s] swizzled

  const int bh = blockIdx.x;
  const int b = bh >> 4, h = bh & 15;
  const int s0 = blockIdx.y * (Ss / NSPLIT);
  const int tid = threadIdx.x;
  const int wave = tid >> 6, lane = tid & 63;
  const int quad = lane >> 4, lm = lane & 15;
  const int F0 = wave * 64;

  // rf fragments in regs (stage-1 B operand): rft[h][F0+ni*16+lm][ks*32+quad*8..+8]
  bf16x8 bfr[4][2];
  {
    const float* rh = rft + (size_t)h * Ff * HDd;
#pragma unroll
    for (int ni = 0; ni < 4; ni++) {
      const float* rrow = rh + (size_t)(F0 + ni * 16 + lm) * HDd;
#pragma unroll
      for (int ks = 0; ks < 2; ks++) {
        float4 a = *reinterpret_cast<const float4*>(rrow + ks * 32 + quad * 8);
        float4 e = *reinterpret_cast<const float4*>(rrow + ks * 32 + quad * 8 + 4);
        union { u32 w[4]; bf16x8 v; } u;
        u.w[0] = pk2(a.x, a.y); u.w[1] = pk2(a.z, a.w);
        u.w[2] = pk2(e.x, e.y); u.w[3] = pk2(e.z, e.w);
        bfr[ni][ks] = u.v;
      }
    }
  }

  // staging geometry: slot j in [0,512): LDS byte j*16; r=j>>3, cs=j&7,
  // source col c = cs ^ (r&7) (involution: swizzled reads recover c=ks*4+quad).
  const int j0 = wave * 64 + lane, j1 = j0 + 256;
  const int r0 = j0 >> 3, c0 = (j0 & 7) ^ (r0 & 7);
  const int r1 = j1 >> 3, c1 = (j1 & 7) ^ (r1 & 7);

  f32x4 kvacc[4][4] = {};
  float kss[4] = {0.f, 0.f, 0.f, 0.f};

#pragma unroll 1
  for (int ch = 0; ch < SCHUNKS; ch++) {
    const int sc = s0 + ch * 64;
    gload_lds16(Km + (size_t)(b * Ss + sc + r0) * Dd + h * 64 + c0 * 8, &KS[(wave * 64) * 8]);
    gload_lds16(Km + (size_t)(b * Ss + sc + r1) * Dd + h * 64 + c1 * 8, &KS[(wave * 64 + 256) * 8]);
    gload_lds16(Vt + (size_t)(h * 64 + r0) * Mm + b * Ss + sc + c0 * 8, &VS[(wave * 64) * 8]);
    gload_lds16(Vt + (size_t)(h * 64 + r1) * Mm + b * Ss + sc + c1 * 8, &VS[(wave * 64 + 256) * 8]);
    __syncthreads();   // drains vmcnt: staged data visible to all waves

    // stage 1 per-mi: P[s-block mi][f F0..F0+63] = K @ rf^T; pmi live only here
#pragma unroll
    for (int mi = 0; mi < 4; mi++) {
      const int row = mi * 16 + lm;                  // s row
      f32x4 pmi[4] = {};
#pragma unroll
      for (int ks2 = 0; ks2 < 2; ks2++) {
        bf16x8 af = *reinterpret_cast<const bf16x8*>(
            (const char*)KS + row * 128 + (((ks2 * 4 + quad) ^ (row & 7)) * 16));
#pragma unroll
        for (int ni = 0; ni < 4; ni++)
          pmi[ni] = __builtin_amdgcn_mfma_f32_16x16x32_bf16(af, bfr[ni][ks2], pmi[ni], 0, 0, 0);
      }
      // softplus + ksum partials + write P^T bf16 into this wave's PT slice
#pragma unroll
      for (int ni = 0; ni < 4; ni++) {
        float v0 = sfast(pmi[ni][0]);
        float v1 = sfast(pmi[ni][1]);
        float v2 = sfast(pmi[ni][2]);
        float v3 = sfast(pmi[ni][3]);
        kss[ni] += (v0 + v1) + (v2 + v3);
        int frow = ni * 16 + lm;                     // f row; s cols = mi*16+quad*4+rr
        int off = (frow * 128 + mi * 32 + quad * 8) ^ ((frow & 7) << 4);
        *reinterpret_cast<uint2*>((char*)&PT[wave][0] + off) =
            make_uint2(pk2(v0, v1), pk2(v2, v3));
      }
    }

    // stage 2: kv[f][d] += P^T @ Vt (own PT + shared VS; 2 k-steps)
#pragma unroll
    for (int ks2 = 0; ks2 < 2; ks2++) {
      bf16x8 a2[4], b2[4];
#pragma unroll
      for (int mi = 0; mi < 4; mi++) {
        int row = mi * 16 + lm;                      // f row
        a2[mi] = *reinterpret_cast<const bf16x8*>(
            (char*)&PT[wave][0] + row * 128 + (((ks2 * 4 + quad) ^ (row & 7)) * 16));
      }
#pragma unroll
      for (int ni = 0; ni < 4; ni++) {
        int row = ni * 16 + lm;                      // d row
        b2[ni] = *reinterpret_cast<const bf16x8*>(
            (const char*)VS + row * 128 + (((ks2 * 4 + quad) ^ (row & 7)) * 16));
      }
#pragma unroll
      for (int mi = 0; mi < 4; mi++)
#pragma unroll
        for (int ni = 0; ni < 4; ni++)
          kvacc[mi][ni] = __builtin_amdgcn_mfma_f32_16x16x32_bf16(a2[mi], b2[ni], kvacc[mi][ni], 0, 0, 0);
    }
    __syncthreads();   // all waves done with KS/VS before next chunk overwrites
  }

  // epilogue: f32 atomics into kv[bh][f][d] and ksum[bh][f]
  float* kvp = kv + (size_t)bh * Ff * HDd;
#pragma unroll
  for (int mi = 0; mi < 4; mi++)
#pragma unroll
    for (int ni = 0; ni < 4; ni++)
#pragma unroll
      for (int rr = 0; rr < 4; rr++) {
        int f = F0 + mi * 16 + quad * 4 + rr;
        int d = ni * 16 + lm;
        atomicAdd(kvp + (size_t)f * HDd + d, kvacc[mi][ni][rr]);
      }
#pragma unroll
  for (int ni = 0; ni < 4; ni++) {
    float v = kss[ni];
    v += __shfl_xor(v, 16, 64);
    v += __shfl_xor(v, 32, 64);
    if (quad == 0) atomicAdd(ksum + (size_t)bh * Ff + F0 + ni * 16 + lm, v);
  }
}

// ============================================================
// kv f32 [bh][f=256][d=64] -> kvT bf16 [bh][d=64][f=256]
// ============================================================
__global__ void kvt_cvt(const float* __restrict__ kv, u16* __restrict__ kvtb)
{
  const int bh = blockIdx.x;
  const int d = threadIdx.x & 63, fg = threadIdx.x >> 6;
  const float* src = kv + (size_t)bh * Ff * HDd + d;
  u32* dst = reinterpret_cast<u32*>(kvtb + (size_t)bh * HDd * Ff + (size_t)d * Ff + fg * 64);
#pragma unroll
  for (int j = 0; j < 32; j++) {
    float v0 = src[(size_t)(fg * 64 + 2 * j) * HDd];
    float v1 = src[(size_t)(fg * 64 + 2 * j + 1) * HDd];
    dst[j] = pk2(v0, v1);
  }
}

// ============================================================
// Fused attention via MFMA (round-4, verified: ASPLIT=16, (256,2)).
// ============================================================
#define ASPLIT 16
#define ACHUNKS (Ss / ASPLIT / 64)   // 4 chunks of 64 rows

__global__ __launch_bounds__(256, 2) void attn_fused(
    const u16* __restrict__ Qm, const float* __restrict__ rft,
    const u16* __restrict__ kvtb, const float* __restrict__ ksum,
    u16* __restrict__ attnb)
{
  __shared__ __align__(16) u16 P4[4][64 * 64];    // 32KB [fb][s][f'] swizzled
  __shared__ __align__(16) float den4[64][4];     // [s][wave] partial denominators

  const int bh = blockIdx.x;
  const int b = bh >> 4, h = bh & 15;
  const int s0 = blockIdx.y * (Ss / ASPLIT);
  const int tid = threadIdx.x;
  const int wave = tid >> 6, lane = tid & 63;
  const int quad = lane >> 4, lm = lane & 15;
  const int F0 = wave * 64;

  // rf fragments (stage-1 B operand): rft[h][F0+ni*16+lm][ks*32+quad*8 ..+8]
  bf16x8 bfr[4][2];
  {
    const float* rh = rft + (size_t)h * Ff * HDd;
#pragma unroll
    for (int ni = 0; ni < 4; ni++) {
      const float* rrow = rh + (size_t)(F0 + ni * 16 + lm) * HDd;
#pragma unroll
      for (int ks = 0; ks < 2; ks++) {
        float4 a = *reinterpret_cast<const float4*>(rrow + ks * 32 + quad * 8);
        float4 e = *reinterpret_cast<const float4*>(rrow + ks * 32 + quad * 8 + 4);
        union { u32 w[4]; bf16x8 v; } u;
        u.w[0] = pk2(a.x, a.y); u.w[1] = pk2(a.z, a.w);
        u.w[2] = pk2(e.x, e.y); u.w[3] = pk2(e.z, e.w);
        bfr[ni][ks] = u.v;
      }
    }
  }
  // kvT fragments (stage-2 B operand): kvtb[bh][wave*16+lm][fb*64+k2*32+quad*8 ..+8]
  bf16x8 b2r[4][2];
  {
    const u16* kb = kvtb + (size_t)bh * HDd * Ff + (size_t)(wave * 16 + lm) * Ff;
#pragma unroll
    for (int fb = 0; fb < 4; fb++)
#pragma unroll
      for (int k2 = 0; k2 < 2; k2++)
        b2r[fb][k2] = *reinterpret_cast<const bf16x8*>(kb + fb * 64 + k2 * 32 + quad * 8);
  }
  // ksum per lane (f = F0 + ni*16 + lm)
  float ksv[4];
#pragma unroll
  for (int ni = 0; ni < 4; ni++)
    ksv[ni] = ksum[(size_t)bh * Ff + F0 + ni * 16 + lm];

  for (int ch = 0; ch < ACHUNKS; ch++) {
    const int sc0 = s0 + ch * 64;

    // stage 1: Q fragments direct from global (read-once), MFMA
    bf16x8 af[4][2];
#pragma unroll
    for (int mi = 0; mi < 4; mi++) {
      const u16* qrow = Qm + (size_t)(b * Ss + sc0 + mi * 16 + lm) * Dd + h * 64;
#pragma unroll
      for (int ks = 0; ks < 2; ks++)
        af[mi][ks] = *reinterpret_cast<const bf16x8*>(qrow + ks * 32 + quad * 8);
    }
    f32x4 p[4][4] = {};
#pragma unroll
    for (int ks = 0; ks < 2; ks++)
#pragma unroll
      for (int mi = 0; mi < 4; mi++)
#pragma unroll
        for (int ni = 0; ni < 4; ni++)
          p[mi][ni] = __builtin_amdgcn_mfma_f32_16x16x32_bf16(af[mi][ks], bfr[ni][ks], p[mi][ni], 0, 0, 0);

    // softplus + cvt_pk round + den partials (from ROUNDED qp) + lane-pair pack
#pragma unroll
    for (int mi = 0; mi < 4; mi++) {
      const int sbase = mi * 16 + quad * 4;
      float dd[4] = {0.f, 0.f, 0.f, 0.f};
#pragma unroll
      for (int ni = 0; ni < 4; ni++) {
        u32 pk01 = pk2(sfast(p[mi][ni][0]), sfast(p[mi][ni][1]));
        u32 pk23 = pk2(sfast(p[mi][ni][2]), sfast(p[mi][ni][3]));
        dd[0] += bflo(pk01) * ksv[ni];
        dd[1] += bfhi(pk01) * ksv[ni];
        dd[2] += bflo(pk23) * ksv[ni];
        dd[3] += bfhi(pk23) * ksv[ni];
        u32 ob01 = (u32)__shfl_xor((int)pk01, 1, 64);
        u32 ob23 = (u32)__shfl_xor((int)pk23, 1, 64);
        const int odd = lm & 1;
        // even lane writes rows sbase+0,1 (r=0,1 pairs); odd lane rows sbase+2,3
        u32 w_a = odd ? ((ob23 & 0xffffu) | (pk23 << 16))
                      : ((pk01 & 0xffffu) | (ob01 << 16));
        u32 w_b = odd ? ((ob23 >> 16)     | (pk23 & 0xffff0000u))
                      : ((pk01 >> 16)     | (ob01 & 0xffff0000u));
        const int row_a = sbase + (odd ? 2 : 0);
        const int row_b = sbase + (odd ? 3 : 1);
        const int fpb = ni * 16 + (lm & ~1);
        const int cc = fpb >> 3;
        const int bib = (fpb & 7) * 2;
        *reinterpret_cast<u32*>((char*)&P4[wave][0] + row_a * 128 + ((cc ^ (row_a & 7)) << 4) + bib) = w_a;
        *reinterpret_cast<u32*>((char*)&P4[wave][0] + row_b * 128 + ((cc ^ (row_b & 7)) << 4) + bib) = w_b;
      }
      // reduce den partials over lm (16-lane groups), write per-wave partial
#pragma unroll
      for (int r = 0; r < 4; r++) {
        float v = dd[r];
        v += __shfl_xor(v, 1, 64);
        v += __shfl_xor(v, 2, 64);
        v += __shfl_xor(v, 4, 64);
        v += __shfl_xor(v, 8, 64);
        if (lm == 0) den4[sbase + r][wave] = v;
      }
    }
    __syncthreads();   // P4 + den4 complete

    // stage 2: attn[s][d] = P @ kvT, waves split by 16-wide d-slices
    f32x4 acc2[4] = {};
#pragma unroll
    for (int fb = 0; fb < 4; fb++)
#pragma unroll
      for (int k2 = 0; k2 < 2; k2++) {
        bf16x8 af2[4];
#pragma unroll
        for (int mi = 0; mi < 4; mi++) {
          int row = mi * 16 + lm;                  // s row
          af2[mi] = *reinterpret_cast<const bf16x8*>(
              (char*)&P4[fb][0] + row * 128 + (((k2 * 4 + quad) ^ (row & 7)) << 4));
        }
#pragma unroll
        for (int mi = 0; mi < 4; mi++)
          acc2[mi] = __builtin_amdgcn_mfma_f32_16x16x32_bf16(af2[mi], b2r[fb][k2], acc2[mi], 0, 0, 0);
      }

    // divide by den, bf16 store: out[s = mi*16+quad*4+r][d = wave*16+lm]
#pragma unroll
    for (int mi = 0; mi < 4; mi++) {
#pragma unroll
      for (int r = 0; r < 4; r++) {
        const int s = mi * 16 + quad * 4 + r;
        float4 dv = *reinterpret_cast<const float4*>(&den4[s][0]);
        const float inv = 1.f / ((dv.x + dv.y) + (dv.z + dv.w) + 1e-8f);
        attnb[(size_t)(b * Ss + sc0 + s) * Dd + h * 64 + wave * 16 + lm] =
            f2b(acc2[mi][r] * inv);
      }
    }
    __syncthreads();   // before next chunk overwrites P4/den4
  }
}

// ============================================================
extern "C" void kernel_launch(void* const* d_in, const int* in_sizes, int n_in,
                              void* d_out, int out_size, void* d_ws, size_t ws_size,
                              hipStream_t stream)
{
  const float* x  = (const float*)d_in[0];
  const float* Wq = (const float*)d_in[1];
  const float* bq = (const float*)d_in[2];
  const float* Wk = (const float*)d_in[3];
  const float* bk = (const float*)d_in[4];
  const float* Wv = (const float*)d_in[5];
  const float* bv = (const float*)d_in[6];
  const float* Wo = (const float*)d_in[7];
  const float* bo = (const float*)d_in[8];
  const float* rf = (const float*)d_in[9];

  // workspace (~147 MB). attn-bf16 ALIASES xb (dead after V^T GEMM);
  // kvT-bf16 ALIASES wqb (dead after Q GEMM).
  char* w = (char*)d_ws;
  u16* xb = (u16*)w;        w += (size_t)Mm * Dd * 2;               // 33.5 MB (also attn-bf16)
  u16* q  = (u16*)w;        w += (size_t)Mm * Dd * 2;               // 33.5 MB
  u16* k  = (u16*)w;        w += (size_t)Mm * Dd * 2;               // 33.5 MB
  u16* vt = (u16*)w;        w += (size_t)Mm * Dd * 2;               // 33.5 MB  V^T [1024][16384]
  u16* wqb = (u16*)w;       w += (size_t)Dd * Dd * 2;               // 2 MB (also kvT bf16)
  u16* wkb = (u16*)w;       w += (size_t)Dd * Dd * 2;
  u16* wvb = (u16*)w;       w += (size_t)Dd * Dd * 2;
  u16* wob = (u16*)w;       w += (size_t)Dd * Dd * 2;
  float* kv = (float*)w;    w += (size_t)(Bb * Hh) * Ff * HDd * 4;  // 4.19 MB
  float* ks = (float*)w;    w += (size_t)(Bb * Hh) * Ff * 4;        // 64 KB
  float* rft = (float*)w;   w += (size_t)Hh * Ff * HDd * 4;         // 1.05 MB
  u16* kvtb = wqb;          // 2 MB alias: kvT bf16 [bh][d][f]

  // f32 -> bf16 conversions
  cvt_bf16<<<(Mm * Dd / 8 + 255) / 256, 256, 0, stream>>>(x, xb, Mm * Dd);
  cvt_bf16<<<(Dd * Dd / 8 + 255) / 256, 256, 0, stream>>>(Wq, wqb, Dd * Dd);
  cvt_bf16<<<(Dd * Dd / 8 + 255) / 256, 256, 0, stream>>>(Wk, wkb, Dd * Dd);
  cvt_bf16<<<(Dd * Dd / 8 + 255) / 256, 256, 0, stream>>>(Wv, wvb, Dd * Dd);
  cvt_bf16<<<(Dd * Dd / 8 + 255) / 256, 256, 0, stream>>>(Wo, wob, Dd * Dd);

  const int nz = (Bb * Hh) * Ff * HDd + (Bb * Hh) * Ff;
  zero_f32<<<(nz + 255) / 256, 256, 0, stream>>>(kv, nz);
  rf_transpose<<<dim3(Hh, HDd), 256, 0, stream>>>(rf, rft);

  const dim3 gg(Mm / 128, Dd / 128);
  mfma_gemm_bt<u16, false><<<gg, 256, 0, stream>>>(xb, wqb, bq, q, Mm, Dd, Dd);
  mfma_gemm_bt<u16, false><<<gg, 256, 0, stream>>>(xb, wkb, bk, k, Mm, Dd, Dd);
  // V^T directly: C[d][m] = sum_k Wv[d][k] x[m][k] + bv[d]  (bias per-row)
  const dim3 gv(Dd / 128, Mm / 128);
  mfma_gemm_bt<u16, true><<<gv, 256, 0, stream>>>(wvb, xb, bv, vt, Dd, Mm, Dd);

  // fused MFMA kv/ksum
  kv_fused<<<dim3(Bb * Hh, NSPLIT), 256, 0, stream>>>(k, vt, rft, kv, ks);

  // kv -> kvT bf16 (into dead wqb region)
  kvt_cvt<<<Bb * Hh, 256, 0, stream>>>(kv, kvtb);

  // fused MFMA attention (writes bf16 into dead xb region)
  attn_fused<<<dim3(Bb * Hh, ASPLIT), 256, 0, stream>>>(q, rft, kvtb, ks, xb);

  // final projection: f32 output
  mfma_gemm_bt<float, false><<<gg, 256, 0, stream>>>(xb, wob, bo, (float*)d_out, Mm, Dd, Dd);
}

// Round 7
// 499.365 us; speedup vs baseline: 1.1389x; 1.0129x over previous
//
#include <hip/hip_runtime.h>
#include <hip/hip_bf16.h>
#include <math.h>

// Problem constants
#define Bb 4
#define Ss 4096
#define Dd 1024
#define Hh 16
#define Ff 256
#define HDd 64
#define Mm (Bb*Ss)          // 16384 rows

typedef unsigned int u32;
typedef unsigned short u16;

typedef __attribute__((ext_vector_type(8))) short bf16x8;   // 8 bf16 = 4 VGPRs
typedef __attribute__((ext_vector_type(4))) float f32x4;

// ---- bf16 helpers ----
__device__ __forceinline__ float bflo(u32 u){ union{u32 i; float f;} c; c.i = u << 16; return c.f; }
__device__ __forceinline__ float bfhi(u32 u){ union{u32 i; float f;} c; c.i = u & 0xffff0000u; return c.f; }
__device__ __forceinline__ u16 f2b(float f){
  union{float f; u32 i;} c; c.f = f;
  u32 x = c.i;
  return (u16)((x + 0x7fffu + ((x >> 16) & 1u)) >> 16);   // RNE
}
// packed f32x2 -> bf16x2 (RNE, compiler emits v_cvt_pk_bf16_f32; same bits as f2b)
__device__ __forceinline__ u32 pk2(float lo, float hi){
  union { __hip_bfloat162 h; u32 u; } c;
  c.h = __float22bfloat162_rn(make_float2(lo, hi));
  return c.u;
}
// fast softplus for the MFMA paths (v_exp/v_log native; err << bf16 noise)
__device__ __forceinline__ float sfast(float x){
  return fmaxf(x, 0.f) + __logf(1.f + __expf(-fabsf(x)));
}
// async global->LDS, 16B per lane: LDS dest = wave-uniform base + lane*16
__device__ __forceinline__ void gload_lds16(const u16* g, u16* l){
  __builtin_amdgcn_global_load_lds(
      (const __attribute__((address_space(1))) void*)g,
      (__attribute__((address_space(3))) void*)l, 16, 0, 0);
}

// ============================================================
// f32 -> bf16 elementwise (8 elems/thread, vectorized)
// ============================================================
__global__ void cvt_bf16(const float* __restrict__ in, u16* __restrict__ out, int n)
{
  int i = (blockIdx.x * 256 + threadIdx.x) * 8;
  if (i >= n) return;
  float4 a = *reinterpret_cast<const float4*>(in + i);
  float4 b = *reinterpret_cast<const float4*>(in + i + 4);
  *reinterpret_cast<uint4*>(out + i) =
      make_uint4(pk2(a.x, a.y), pk2(a.z, a.w), pk2(b.x, b.y), pk2(b.z, b.w));
}

// merged 4-weight cvt: dsts are contiguous (wqb|wkb|wvb|wob), src by blockIdx.y
__global__ void cvt_w4(const float* __restrict__ w0, const float* __restrict__ w1,
                       const float* __restrict__ w2, const float* __restrict__ w3,
                       u16* __restrict__ out)
{
  const int y = blockIdx.y;
  const float* in = (y == 0) ? w0 : (y == 1) ? w1 : (y == 2) ? w2 : w3;
  int i = (blockIdx.x * 256 + threadIdx.x) * 8;
  float4 a = *reinterpret_cast<const float4*>(in + i);
  float4 b = *reinterpret_cast<const float4*>(in + i + 4);
  *reinterpret_cast<uint4*>(out + (size_t)y * Dd * Dd + i) =
      make_uint4(pk2(a.x, a.y), pk2(a.z, a.w), pk2(b.x, b.y), pk2(b.z, b.w));
}

// ============================================================
// zero-fill (ws is re-poisoned 0xAA each call)
// ============================================================
__global__ void zero_f32(float* __restrict__ p, int n)
{
  int i = blockIdx.x * 256 + threadIdx.x;
  if (i < n) p[i] = 0.f;
}

// ============================================================
// MFMA GEMM: C[M,N] = A[M,K](bf16) * W[N,K]^T(bf16) + bias
// Round-7: BK=64 (16 iters instead of 32 -> half the barrier drains) with
// XOR-swizzled LDS via pre-swizzled gload_lds SOURCE (lifted verbatim from
// the r6-verified kv_fused staging; rule 21 involution). Frag-read bank
// pattern after swizzle: 2-way (free). MFMA order per (mi,ni) unchanged
// (k ascending in 32-slices) -> bit-identical C.
// Frag layouts (m89/m91/m120): A[m=lane&15][k], B[k][n=lane&15],
// D[row=quad*4+r][col=lane&15].
// ============================================================
template<typename OT, bool BROW>
__global__ __launch_bounds__(256, 2) void mfma_gemm_bt(
    const u16* __restrict__ A, const u16* __restrict__ W,
    const float* __restrict__ bias, OT* __restrict__ C,
    int M, int N, int K)
{
  __shared__ __align__(16) u16 As[128 * 64];   // 16KB, [row][64] swizzled
  __shared__ __align__(16) u16 Bs[128 * 64];   // 16KB

  const int tid = threadIdx.x;
  const int wave = tid >> 6, lane = tid & 63;
  const int quad = lane >> 4, lm = lane & 15;
  const int wm = (wave >> 1) * 64, wn = (wave & 1) * 64;
  const int m0 = blockIdx.x * 128, n0 = blockIdx.y * 128;

  // staging geometry: 1024 slots of 16B per tile; slot j: r=j>>3, cs=j&7,
  // source col c = cs ^ (r&7). Wave w, instr i covers slots w*64+lane+i*256.
  int rr[4], cc4[4];
#pragma unroll
  for (int i = 0; i < 4; i++) {
    const int j = wave * 64 + i * 256 + lane;
    rr[i] = j >> 3;
    cc4[i] = (j & 7) ^ (rr[i] & 7);
  }

  f32x4 acc[4][4] = {};   // zero-init

  for (int k0 = 0; k0 < K; k0 += 64) {
#pragma unroll
    for (int i = 0; i < 4; i++) {
      u16* ldsA = &As[(wave * 64 + i * 256) * 8];   // wave-uniform base
      u16* ldsB = &Bs[(wave * 64 + i * 256) * 8];
      gload_lds16(A + (size_t)(m0 + rr[i]) * K + k0 + cc4[i] * 8, ldsA);
      gload_lds16(W + (size_t)(n0 + rr[i]) * K + k0 + cc4[i] * 8, ldsB);
    }
    __syncthreads();   // implicit vmcnt(0) drain completes the LDS writes

#pragma unroll
    for (int ks2 = 0; ks2 < 2; ks2++) {
      bf16x8 af[4], bf[4];
#pragma unroll
      for (int mi = 0; mi < 4; mi++) {
        const int row = wm + mi * 16 + lm;
        af[mi] = *reinterpret_cast<const bf16x8*>(
            &As[row * 64 + (((ks2 * 4 + quad) ^ (row & 7)) * 8)]);
      }
#pragma unroll
      for (int ni = 0; ni < 4; ni++) {
        const int row = wn + ni * 16 + lm;
        bf[ni] = *reinterpret_cast<const bf16x8*>(
            &Bs[row * 64 + (((ks2 * 4 + quad) ^ (row & 7)) * 8)]);
      }
#pragma unroll
      for (int mi = 0; mi < 4; mi++)
#pragma unroll
        for (int ni = 0; ni < 4; ni++)
          acc[mi][ni] = __builtin_amdgcn_mfma_f32_16x16x32_bf16(af[mi], bf[ni], acc[mi][ni], 0, 0, 0);
    }
    __syncthreads();
  }

  // epilogue: lane l, reg r -> C[m0+wm+mi*16+quad*4+r][n0+wn+ni*16+lm]
#pragma unroll
  for (int mi = 0; mi < 4; mi++)
#pragma unroll
    for (int ni = 0; ni < 4; ni++) {
      const int n = n0 + wn + ni * 16 + lm;
      const float bvn = BROW ? 0.f : bias[n];
      const int mb = m0 + wm + mi * 16 + quad * 4;
      float v[4];
#pragma unroll
      for (int r = 0; r < 4; r++)
        v[r] = acc[mi][ni][r] + (BROW ? bias[mb + r] : bvn);
      if constexpr (sizeof(OT) == 2) {
        const u32 w01 = pk2(v[0], v[1]), w23 = pk2(v[2], v[3]);
        ((u16*)C)[(size_t)(mb + 0) * N + n] = (u16)w01;
        ((u16*)C)[(size_t)(mb + 1) * N + n] = (u16)(w01 >> 16);
        ((u16*)C)[(size_t)(mb + 2) * N + n] = (u16)w23;
        ((u16*)C)[(size_t)(mb + 3) * N + n] = (u16)(w23 >> 16);
      } else {
#pragma unroll
        for (int r = 0; r < 4; r++)
          ((float*)C)[(size_t)(mb + r) * N + n] = v[r];
      }
    }
}

// ============================================================
// rf [H][HD][F] f32 -> rft [H][F][HD] f32 (contiguous wave-uniform rows)
// ============================================================
__global__ void rf_transpose(const float* __restrict__ rf, float* __restrict__ rft)
{
  const int h = blockIdx.x, d = blockIdx.y, f = threadIdx.x;
  rft[((size_t)h * Ff + f) * HDd + d] = rf[((size_t)(h * HDd + d)) * Ff + f];
}

// ============================================================
// Fused kv/ksum via MFMA (round-6, verified).
// ============================================================
#define NSPLIT 16
#define SCHUNKS (Ss / NSPLIT / 64)   // 4 chunks of 64 rows

__global__ __launch_bounds__(256, 2) void kv_fused(
    const u16* __restrict__ Km, const u16* __restrict__ Vt,
    const float* __restrict__ rft, float* __restrict__ kv, float* __restrict__ ksum)
{
  __shared__ __align__(16) u16 KS[64 * 64];       // 8KB  K chunk [s][d] swizzled
  __shared__ __align__(16) u16 VS[64 * 64];       // 8KB  Vt chunk [d][s] swizzled
  __shared__ __align__(16) u16 PT[4][64 * 64];    // 32KB per-wave P^T [f][s] swizzled

  const int bh = blockIdx.x;
  const int b = bh >> 4, h = bh & 15;
  const int s0 = blockIdx.y * (Ss / NSPLIT);
  const int tid = threadIdx.x;
  const int wave = tid >> 6, lane = tid & 63;
  const int quad = lane >> 4, lm = lane & 15;
  const int F0 = wave * 64;

  // rf fragments in regs (stage-1 B operand): rft[h][F0+ni*16+lm][ks*32+quad*8..+8]
  bf16x8 bfr[4][2];
  {
    const float* rh = rft + (size_t)h * Ff * HDd;
#pragma unroll
    for (int ni = 0; ni < 4; ni++) {
      const float* rrow = rh + (size_t)(F0 + ni * 16 + lm) * HDd;
#pragma unroll
      for (int ks = 0; ks < 2; ks++) {
        float4 a = *reinterpret_cast<const float4*>(rrow + ks * 32 + quad * 8);
        float4 e = *reinterpret_cast<const float4*>(rrow + ks * 32 + quad * 8 + 4);
        union { u32 w[4]; bf16x8 v; } u;
        u.w[0] = pk2(a.x, a.y); u.w[1] = pk2(a.z, a.w);
        u.w[2] = pk2(e.x, e.y); u.w[3] = pk2(e.z, e.w);
        bfr[ni][ks] = u.v;
      }
    }
  }

  // staging geometry: slot j in [0,512): LDS byte j*16; r=j>>3, cs=j&7,
  // source col c = cs ^ (r&7) (involution: swizzled reads recover c=ks*4+quad).
  const int j0 = wave * 64 + lane, j1 = j0 + 256;
  const int r0 = j0 >> 3, c0 = (j0 & 7) ^ (r0 & 7);
  const int r1 = j1 >> 3, c1 = (j1 & 7) ^ (r1 & 7);

  f32x4 kvacc[4][4] = {};
  float kss[4] = {0.f, 0.f, 0.f, 0.f};

#pragma unroll 1
  for (int ch = 0; ch < SCHUNKS; ch++) {
    const int sc = s0 + ch * 64;
    gload_lds16(Km + (size_t)(b * Ss + sc + r0) * Dd + h * 64 + c0 * 8, &KS[(wave * 64) * 8]);
    gload_lds16(Km + (size_t)(b * Ss + sc + r1) * Dd + h * 64 + c1 * 8, &KS[(wave * 64 + 256) * 8]);
    gload_lds16(Vt + (size_t)(h * 64 + r0) * Mm + b * Ss + sc + c0 * 8, &VS[(wave * 64) * 8]);
    gload_lds16(Vt + (size_t)(h * 64 + r1) * Mm + b * Ss + sc + c1 * 8, &VS[(wave * 64 + 256) * 8]);
    __syncthreads();   // drains vmcnt: staged data visible to all waves

    // stage 1 per-mi: P[s-block mi][f F0..F0+63] = K @ rf^T; pmi live only here
#pragma unroll
    for (int mi = 0; mi < 4; mi++) {
      const int row = mi * 16 + lm;                  // s row
      f32x4 pmi[4] = {};
#pragma unroll
      for (int ks2 = 0; ks2 < 2; ks2++) {
        bf16x8 af = *reinterpret_cast<const bf16x8*>(
            (const char*)KS + row * 128 + (((ks2 * 4 + quad) ^ (row & 7)) * 16));
#pragma unroll
        for (int ni = 0; ni < 4; ni++)
          pmi[ni] = __builtin_amdgcn_mfma_f32_16x16x32_bf16(af, bfr[ni][ks2], pmi[ni], 0, 0, 0);
      }
      // softplus + ksum partials + write P^T bf16 into this wave's PT slice
#pragma unroll
      for (int ni = 0; ni < 4; ni++) {
        float v0 = sfast(pmi[ni][0]);
        float v1 = sfast(pmi[ni][1]);
        float v2 = sfast(pmi[ni][2]);
        float v3 = sfast(pmi[ni][3]);
        kss[ni] += (v0 + v1) + (v2 + v3);
        int frow = ni * 16 + lm;                     // f row; s cols = mi*16+quad*4+rr
        int off = (frow * 128 + mi * 32 + quad * 8) ^ ((frow & 7) << 4);
        *reinterpret_cast<uint2*>((char*)&PT[wave][0] + off) =
            make_uint2(pk2(v0, v1), pk2(v2, v3));
      }
    }

    // stage 2: kv[f][d] += P^T @ Vt (own PT + shared VS; 2 k-steps)
#pragma unroll
    for (int ks2 = 0; ks2 < 2; ks2++) {
      bf16x8 a2[4], b2[4];
#pragma unroll
      for (int mi = 0; mi < 4; mi++) {
        int row = mi * 16 + lm;                      // f row
        a2[mi] = *reinterpret_cast<const bf16x8*>(
            (char*)&PT[wave][0] + row * 128 + (((ks2 * 4 + quad) ^ (row & 7)) * 16));
      }
#pragma unroll
      for (int ni = 0; ni < 4; ni++) {
        int row = ni * 16 + lm;                      // d row
        b2[ni] = *reinterpret_cast<const bf16x8*>(
            (const char*)VS + row * 128 + (((ks2 * 4 + quad) ^ (row & 7)) * 16));
      }
#pragma unroll
      for (int mi = 0; mi < 4; mi++)
#pragma unroll
        for (int ni = 0; ni < 4; ni++)
          kvacc[mi][ni] = __builtin_amdgcn_mfma_f32_16x16x32_bf16(a2[mi], b2[ni], kvacc[mi][ni], 0, 0, 0);
    }
    __syncthreads();   // all waves done with KS/VS before next chunk overwrites
  }

  // epilogue: f32 atomics into kv[bh][f][d] and ksum[bh][f]
  float* kvp = kv + (size_t)bh * Ff * HDd;
#pragma unroll
  for (int mi = 0; mi < 4; mi++)
#pragma unroll
    for (int ni = 0; ni < 4; ni++)
#pragma unroll
      for (int rr2 = 0; rr2 < 4; rr2++) {
        int f = F0 + mi * 16 + quad * 4 + rr2;
        int d = ni * 16 + lm;
        atomicAdd(kvp + (size_t)f * HDd + d, kvacc[mi][ni][rr2]);
      }
#pragma unroll
  for (int ni = 0; ni < 4; ni++) {
    float v = kss[ni];
    v += __shfl_xor(v, 16, 64);
    v += __shfl_xor(v, 32, 64);
    if (quad == 0) atomicAdd(ksum + (size_t)bh * Ff + F0 + ni * 16 + lm, v);
  }
}

// ============================================================
// kv f32 [bh][f=256][d=64] -> kvT bf16 [bh][d=64][f=256]
// ============================================================
__global__ void kvt_cvt(const float* __restrict__ kv, u16* __restrict__ kvtb)
{
  const int bh = blockIdx.x;
  const int d = threadIdx.x & 63, fg = threadIdx.x >> 6;
  const float* src = kv + (size_t)bh * Ff * HDd + d;
  u32* dst = reinterpret_cast<u32*>(kvtb + (size_t)bh * HDd * Ff + (size_t)d * Ff + fg * 64);
#pragma unroll
  for (int j = 0; j < 32; j++) {
    float v0 = src[(size_t)(fg * 64 + 2 * j) * HDd];
    float v1 = src[(size_t)(fg * 64 + 2 * j + 1) * HDd];
    dst[j] = pk2(v0, v1);
  }
}

// ============================================================
// Fused attention via MFMA. Round-7 VALU shave (structure unchanged):
//  * P4 write offsets hoisted out of the chunk loop (chunk-invariant;
//    mi*2048 folds into the ds-write immediate)
//  * w_a/w_b pack via 2 cndmask + 2 v_perm_b32 (was ~8 ops of masks/shifts)
//  * final-store cvt via pk2 pairs (1 op/2 elems vs 4-op f2b) — same RNE bits
// ============================================================
#define ASPLIT 16
#define ACHUNKS (Ss / ASPLIT / 64)   // 4 chunks of 64 rows

__global__ __launch_bounds__(256, 2) void attn_fused(
    const u16* __restrict__ Qm, const float* __restrict__ rft,
    const u16* __restrict__ kvtb, const float* __restrict__ ksum,
    u16* __restrict__ attnb)
{
  __shared__ __align__(16) u16 P4[4][64 * 64];    // 32KB [fb][s][f'] swizzled
  __shared__ __align__(16) float den4[64][4];     // [s][wave] partial denominators

  const int bh = blockIdx.x;
  const int b = bh >> 4, h = bh & 15;
  const int s0 = blockIdx.y * (Ss / ASPLIT);
  const int tid = threadIdx.x;
  const int wave = tid >> 6, lane = tid & 63;
  const int quad = lane >> 4, lm = lane & 15;
  const int F0 = wave * 64;

  // rf fragments (stage-1 B operand): rft[h][F0+ni*16+lm][ks*32+quad*8 ..+8]
  bf16x8 bfr[4][2];
  {
    const float* rh = rft + (size_t)h * Ff * HDd;
#pragma unroll
    for (int ni = 0; ni < 4; ni++) {
      const float* rrow = rh + (size_t)(F0 + ni * 16 + lm) * HDd;
#pragma unroll
      for (int ks = 0; ks < 2; ks++) {
        float4 a = *reinterpret_cast<const float4*>(rrow + ks * 32 + quad * 8);
        float4 e = *reinterpret_cast<const float4*>(rrow + ks * 32 + quad * 8 + 4);
        union { u32 w[4]; bf16x8 v; } u;
        u.w[0] = pk2(a.x, a.y); u.w[1] = pk2(a.z, a.w);
        u.w[2] = pk2(e.x, e.y); u.w[3] = pk2(e.z, e.w);
        bfr[ni][ks] = u.v;
      }
    }
  }
  // kvT fragments (stage-2 B operand): kvtb[bh][wave*16+lm][fb*64+k2*32+quad*8 ..+8]
  bf16x8 b2r[4][2];
  {
    const u16* kb = kvtb + (size_t)bh * HDd * Ff + (size_t)(wave * 16 + lm) * Ff;
#pragma unroll
    for (int fb = 0; fb < 4; fb++)
#pragma unroll
      for (int k2 = 0; k2 < 2; k2++)
        b2r[fb][k2] = *reinterpret_cast<const bf16x8*>(kb + fb * 64 + k2 * 32 + quad * 8);
  }
  // ksum per lane (f = F0 + ni*16 + lm)
  float ksv[4];
#pragma unroll
  for (int ni = 0; ni < 4; ni++)
    ksv[ni] = ksum[(size_t)bh * Ff + F0 + ni * 16 + lm];

  // chunk-invariant P4 write offsets (old: off = row*128 + ((cc^(row&7))<<4)+bib
  // with row = mi*16 + quad*4 + {oa,ob}; mi*16 ≡ 0 mod 8 so the XOR term is
  // mi-independent and mi contributes exactly +mi*2048 bytes)
  const int odd = lm & 1;
  u32 pOffA[4], pOffB[4];
  char* const ptb = (char*)&P4[wave][0];
  {
    const int ra = quad * 4 + (odd ? 2 : 0);
    const int rb = quad * 4 + (odd ? 3 : 1);
#pragma unroll
    for (int ni = 0; ni < 4; ni++) {
      const int fpb = ni * 16 + (lm & ~1);
      const int cc = fpb >> 3, bib = (fpb & 7) * 2;
      pOffA[ni] = ra * 128 + ((cc ^ (ra & 7)) << 4) + bib;
      pOffB[ni] = rb * 128 + ((cc ^ (rb & 7)) << 4) + bib;
    }
  }

  for (int ch = 0; ch < ACHUNKS; ch++) {
    const int sc0 = s0 + ch * 64;

    // stage 1: Q fragments direct from global (read-once), MFMA
    bf16x8 af[4][2];
#pragma unroll
    for (int mi = 0; mi < 4; mi++) {
      const u16* qrow = Qm + (size_t)(b * Ss + sc0 + mi * 16 + lm) * Dd + h * 64;
#pragma unroll
      for (int ks = 0; ks < 2; ks++)
        af[mi][ks] = *reinterpret_cast<const bf16x8*>(qrow + ks * 32 + quad * 8);
    }
    f32x4 p[4][4] = {};
#pragma unroll
    for (int ks = 0; ks < 2; ks++)
#pragma unroll
      for (int mi = 0; mi < 4; mi++)
#pragma unroll
        for (int ni = 0; ni < 4; ni++)
          p[mi][ni] = __builtin_amdgcn_mfma_f32_16x16x32_bf16(af[mi][ks], bfr[ni][ks], p[mi][ni], 0, 0, 0);

    // softplus + cvt_pk round + den partials (from ROUNDED qp) + perm pack
#pragma unroll
    for (int mi = 0; mi < 4; mi++) {
      const int sbase = mi * 16 + quad * 4;
      float dd[4] = {0.f, 0.f, 0.f, 0.f};
#pragma unroll
      for (int ni = 0; ni < 4; ni++) {
        u32 pk01 = pk2(sfast(p[mi][ni][0]), sfast(p[mi][ni][1]));
        u32 pk23 = pk2(sfast(p[mi][ni][2]), sfast(p[mi][ni][3]));
        dd[0] += bflo(pk01) * ksv[ni];
        dd[1] += bfhi(pk01) * ksv[ni];
        dd[2] += bflo(pk23) * ksv[ni];
        dd[3] += bfhi(pk23) * ksv[ni];
        u32 ob01 = (u32)__shfl_xor((int)pk01, 1, 64);
        u32 ob23 = (u32)__shfl_xor((int)pk23, 1, 64);
        // even lane: w_a = lo(pk01)|lo(ob01)<<16, w_b = hi(pk01)|hi(ob01)<<16 (hi in place)
        // odd lane:  sources swap to (ob23, pk23) — 2 cndmask + 2 v_perm_b32
        u32 s0v = odd ? ob23 : pk01;
        u32 s1v = odd ? pk23 : ob01;
        u32 w_a = __builtin_amdgcn_perm(s1v, s0v, 0x05040100u);   // lo16(s0)|lo16(s1)<<16
        u32 w_b = __builtin_amdgcn_perm(s1v, s0v, 0x07060302u);   // hi16(s0)|hi16(s1)<<16
        *reinterpret_cast<u32*>(ptb + pOffA[ni] + mi * 2048) = w_a;
        *reinterpret_cast<u32*>(ptb + pOffB[ni] + mi * 2048) = w_b;
      }
      // reduce den partials over lm (16-lane groups), write per-wave partial
#pragma unroll
      for (int r = 0; r < 4; r++) {
        float v = dd[r];
        v += __shfl_xor(v, 1, 64);
        v += __shfl_xor(v, 2, 64);
        v += __shfl_xor(v, 4, 64);
        v += __shfl_xor(v, 8, 64);
        if (lm == 0) den4[sbase + r][wave] = v;
      }
    }
    __syncthreads();   // P4 + den4 complete

    // stage 2: attn[s][d] = P @ kvT, waves split by 16-wide d-slices
    f32x4 acc2[4] = {};
#pragma unroll
    for (int fb = 0; fb < 4; fb++)
#pragma unroll
      for (int k2 = 0; k2 < 2; k2++) {
        bf16x8 af2[4];
#pragma unroll
        for (int mi = 0; mi < 4; mi++) {
          int row = mi * 16 + lm;                  // s row
          af2[mi] = *reinterpret_cast<const bf16x8*>(
              (char*)&P4[fb][0] + row * 128 + (((k2 * 4 + quad) ^ (row & 7)) << 4));
        }
#pragma unroll
        for (int mi = 0; mi < 4; mi++)
          acc2[mi] = __builtin_amdgcn_mfma_f32_16x16x32_bf16(af2[mi], b2r[fb][k2], acc2[mi], 0, 0, 0);
      }

    // divide by den, pk2-pair cvt, bf16 store: out[s=mi*16+quad*4+r][d=wave*16+lm]
#pragma unroll
    for (int mi = 0; mi < 4; mi++) {
      float o[4];
#pragma unroll
      for (int r = 0; r < 4; r++) {
        const int s = mi * 16 + quad * 4 + r;
        float4 dv = *reinterpret_cast<const float4*>(&den4[s][0]);
        const float inv = 1.f / ((dv.x + dv.y) + (dv.z + dv.w) + 1e-8f);
        o[r] = acc2[mi][r] * inv;
      }
      const u32 w01 = pk2(o[0], o[1]), w23 = pk2(o[2], o[3]);
      const size_t ob = (size_t)(b * Ss + sc0 + mi * 16 + quad * 4) * Dd + h * 64 + wave * 16 + lm;
      attnb[ob]          = (u16)w01;
      attnb[ob + Dd]     = (u16)(w01 >> 16);
      attnb[ob + 2 * Dd] = (u16)w23;
      attnb[ob + 3 * Dd] = (u16)(w23 >> 16);
    }
    __syncthreads();   // before next chunk overwrites P4/den4
  }
}

// ============================================================
extern "C" void kernel_launch(void* const* d_in, const int* in_sizes, int n_in,
                              void* d_out, int out_size, void* d_ws, size_t ws_size,
                              hipStream_t stream)
{
  const float* x  = (const float*)d_in[0];
  const float* Wq = (const float*)d_in[1];
  const float* bq = (const float*)d_in[2];
  const float* Wk = (const float*)d_in[3];
  const float* bk = (const float*)d_in[4];
  const float* Wv = (const float*)d_in[5];
  const float* bv = (const float*)d_in[6];
  const float* Wo = (const float*)d_in[7];
  const float* bo = (const float*)d_in[8];
  const float* rf = (const float*)d_in[9];

  // workspace (~147 MB). attn-bf16 ALIASES xb (dead after V^T GEMM);
  // kvT-bf16 ALIASES wqb (dead after Q GEMM).
  char* w = (char*)d_ws;
  u16* xb = (u16*)w;        w += (size_t)Mm * Dd * 2;               // 33.5 MB (also attn-bf16)
  u16* q  = (u16*)w;        w += (size_t)Mm * Dd * 2;               // 33.5 MB
  u16* k  = (u16*)w;        w += (size_t)Mm * Dd * 2;               // 33.5 MB
  u16* vt = (u16*)w;        w += (size_t)Mm * Dd * 2;               // 33.5 MB  V^T [1024][16384]
  u16* wqb = (u16*)w;       w += (size_t)Dd * Dd * 2;               // 2 MB (also kvT bf16)
  u16* wkb = (u16*)w;       w += (size_t)Dd * Dd * 2;
  u16* wvb = (u16*)w;       w += (size_t)Dd * Dd * 2;
  u16* wob = (u16*)w;       w += (size_t)Dd * Dd * 2;
  float* kv = (float*)w;    w += (size_t)(Bb * Hh) * Ff * HDd * 4;  // 4.19 MB
  float* ks = (float*)w;    w += (size_t)(Bb * Hh) * Ff * 4;        // 64 KB
  float* rft = (float*)w;   w += (size_t)Hh * Ff * HDd * 4;         // 1.05 MB
  u16* kvtb = wqb;          // 2 MB alias: kvT bf16 [bh][d][f]

  // f32 -> bf16 conversions (weights merged into one launch; dsts contiguous)
  cvt_bf16<<<(Mm * Dd / 8 + 255) / 256, 256, 0, stream>>>(x, xb, Mm * Dd);
  cvt_w4<<<dim3(Dd * Dd / 8 / 256, 4), 256, 0, stream>>>(Wq, Wk, Wv, Wo, wqb);

  const int nz = (Bb * Hh) * Ff * HDd + (Bb * Hh) * Ff;
  zero_f32<<<(nz + 255) / 256, 256, 0, stream>>>(kv, nz);
  rf_transpose<<<dim3(Hh, HDd), 256, 0, stream>>>(rf, rft);

  const dim3 gg(Mm / 128, Dd / 128);
  mfma_gemm_bt<u16, false><<<gg, 256, 0, stream>>>(xb, wqb, bq, q, Mm, Dd, Dd);
  mfma_gemm_bt<u16, false><<<gg, 256, 0, stream>>>(xb, wkb, bk, k, Mm, Dd, Dd);
  // V^T directly: C[d][m] = sum_k Wv[d][k] x[m][k] + bv[d]  (bias per-row)
  const dim3 gv(Dd / 128, Mm / 128);
  mfma_gemm_bt<u16, true><<<gv, 256, 0, stream>>>(wvb, xb, bv, vt, Dd, Mm, Dd);

  // fused MFMA kv/ksum
  kv_fused<<<dim3(Bb * Hh, NSPLIT), 256, 0, stream>>>(k, vt, rft, kv, ks);

  // kv -> kvT bf16 (into dead wqb region)
  kvt_cvt<<<Bb * Hh, 256, 0, stream>>>(kv, kvtb);

  // fused MFMA attention (writes bf16 into dead xb region)
  attn_fused<<<dim3(Bb * Hh, ASPLIT), 256, 0, stream>>>(q, rft, kvtb, ks, xb);

  // final projection: f32 output
  mfma_gemm_bt<float, false><<<gg, 256, 0, stream>>>(xb, wob, bo, (float*)d_out, Mm, Dd, Dd);
}

// Round 8
// 492.925 us; speedup vs baseline: 1.1538x; 1.0131x over previous
//
#include <hip/hip_runtime.h>
#include <hip/hip_bf16.h>
#include <math.h>

// Problem constants
#define Bb 4
#define Ss 4096
#define Dd 1024
#define Hh 16
#define Ff 256
#define HDd 64
#define Mm (Bb*Ss)          // 16384 rows

typedef unsigned int u32;
typedef unsigned short u16;

typedef __attribute__((ext_vector_type(8))) short bf16x8;   // 8 bf16 = 4 VGPRs
typedef __attribute__((ext_vector_type(4))) float f32x4;

// ---- bf16 helpers ----
__device__ __forceinline__ float bflo(u32 u){ union{u32 i; float f;} c; c.i = u << 16; return c.f; }
__device__ __forceinline__ float bfhi(u32 u){ union{u32 i; float f;} c; c.i = u & 0xffff0000u; return c.f; }
__device__ __forceinline__ u16 f2b(float f){
  union{float f; u32 i;} c; c.f = f;
  u32 x = c.i;
  return (u16)((x + 0x7fffu + ((x >> 16) & 1u)) >> 16);   // RNE
}
// packed f32x2 -> bf16x2 (RNE, compiler emits v_cvt_pk_bf16_f32; same bits as f2b)
__device__ __forceinline__ u32 pk2(float lo, float hi){
  union { __hip_bfloat162 h; u32 u; } c;
  c.h = __float22bfloat162_rn(make_float2(lo, hi));
  return c.u;
}
// fast softplus for the MFMA paths (v_exp/v_log native; err << bf16 noise)
__device__ __forceinline__ float sfast(float x){
  return fmaxf(x, 0.f) + __logf(1.f + __expf(-fabsf(x)));
}
// async global->LDS, 16B per lane: LDS dest = wave-uniform base + lane*16
__device__ __forceinline__ void gload_lds16(const u16* g, u16* l){
  __builtin_amdgcn_global_load_lds(
      (const __attribute__((address_space(1))) void*)g,
      (__attribute__((address_space(3))) void*)l, 16, 0, 0);
}

// ============================================================
// f32 -> bf16 elementwise (8 elems/thread, vectorized)
// ============================================================
__global__ void cvt_bf16(const float* __restrict__ in, u16* __restrict__ out, int n)
{
  int i = (blockIdx.x * 256 + threadIdx.x) * 8;
  if (i >= n) return;
  float4 a = *reinterpret_cast<const float4*>(in + i);
  float4 b = *reinterpret_cast<const float4*>(in + i + 4);
  *reinterpret_cast<uint4*>(out + i) =
      make_uint4(pk2(a.x, a.y), pk2(a.z, a.w), pk2(b.x, b.y), pk2(b.z, b.w));
}

// merged 4-weight cvt: dsts are contiguous (wqb|wkb|wvb|wob), src by blockIdx.y
__global__ void cvt_w4(const float* __restrict__ w0, const float* __restrict__ w1,
                       const float* __restrict__ w2, const float* __restrict__ w3,
                       u16* __restrict__ out)
{
  const int y = blockIdx.y;
  const float* in = (y == 0) ? w0 : (y == 1) ? w1 : (y == 2) ? w2 : w3;
  int i = (blockIdx.x * 256 + threadIdx.x) * 8;
  float4 a = *reinterpret_cast<const float4*>(in + i);
  float4 b = *reinterpret_cast<const float4*>(in + i + 4);
  *reinterpret_cast<uint4*>(out + (size_t)y * Dd * Dd + i) =
      make_uint4(pk2(a.x, a.y), pk2(a.z, a.w), pk2(b.x, b.y), pk2(b.z, b.w));
}

// ============================================================
// zero-fill (ws is re-poisoned 0xAA each call)
// ============================================================
__global__ void zero_f32(float* __restrict__ p, int n)
{
  int i = blockIdx.x * 256 + threadIdx.x;
  if (i < n) p[i] = 0.f;
}

// ============================================================
// MFMA GEMM: C[M,N] = A[M,K](bf16) * W[N,K]^T(bf16) + bias
// Round-8: DOUBLE-BUFFERED gload_lds staging with counted vmcnt(8) and
// two raw barriers per K-iter (the r5-kv-proven 2-barrier dbuf pattern;
// zero extra registers since staging is gload_lds-direct). Next tile's 8
// loads stay in flight across the barrier, hiding HBM/L3 latency under
// the current tile's 32 MFMAs. BK=64, XOR-swizzled LDS via pre-swizzled
// source (rule 21 involution). LDS 64KB -> 2 blocks/CU (= current
// reg-capped occupancy, so no occupancy loss).
// Frag layouts (m89/m91/m120): A[m=lane&15][k], B[k][n=lane&15],
// D[row=quad*4+r][col=lane&15].
// ============================================================
template<typename OT, bool BROW>
__global__ __launch_bounds__(256, 2) void mfma_gemm_bt(
    const u16* __restrict__ A, const u16* __restrict__ W,
    const float* __restrict__ bias, OT* __restrict__ C,
    int M, int N, int K)
{
  __shared__ __align__(16) u16 As[2][128 * 64];   // 2x16KB, [row][64] swizzled
  __shared__ __align__(16) u16 Bs[2][128 * 64];   // 2x16KB

  const int tid = threadIdx.x;
  const int wave = tid >> 6, lane = tid & 63;
  const int quad = lane >> 4, lm = lane & 15;
  const int wm = (wave >> 1) * 64, wn = (wave & 1) * 64;
  const int m0 = blockIdx.x * 128, n0 = blockIdx.y * 128;

  // staging geometry: 1024 slots of 16B per tile; slot j: r=j>>3, cs=j&7,
  // source col c = cs ^ (r&7). Wave w, instr i covers slots w*64+lane+i*256.
  int rr[4], cc4[4];
#pragma unroll
  for (int i = 0; i < 4; i++) {
    const int j = wave * 64 + i * 256 + lane;
    rr[i] = j >> 3;
    cc4[i] = (j & 7) ^ (rr[i] & 7);
  }

  f32x4 acc[4][4] = {};   // zero-init

  // prologue: stage tile 0 into buf 0
#pragma unroll
  for (int i = 0; i < 4; i++) {
    gload_lds16(A + (size_t)(m0 + rr[i]) * K + cc4[i] * 8, &As[0][(wave * 64 + i * 256) * 8]);
    gload_lds16(W + (size_t)(n0 + rr[i]) * K + cc4[i] * 8, &Bs[0][(wave * 64 + i * 256) * 8]);
  }

  const int NIT = K >> 6;   // 16 K-iters of BK=64
#pragma unroll 1
  for (int it = 0; it < NIT; it++) {
    const int cur = it & 1;
    if (it + 1 < NIT) {
      const int k1 = (it + 1) * 64;
#pragma unroll
      for (int i = 0; i < 4; i++) {
        gload_lds16(A + (size_t)(m0 + rr[i]) * K + k1 + cc4[i] * 8,
                    &As[cur ^ 1][(wave * 64 + i * 256) * 8]);
        gload_lds16(W + (size_t)(n0 + rr[i]) * K + k1 + cc4[i] * 8,
                    &Bs[cur ^ 1][(wave * 64 + i * 256) * 8]);
      }
      asm volatile("s_waitcnt vmcnt(8)" ::: "memory");   // wait only cur tile's 8
    } else {
      asm volatile("s_waitcnt vmcnt(0)" ::: "memory");
    }
    __builtin_amdgcn_s_barrier();                        // cur tile visible to all waves
    __builtin_amdgcn_sched_barrier(0);

    const u16* Ac = &As[cur][0];
    const u16* Bc = &Bs[cur][0];
#pragma unroll
    for (int ks2 = 0; ks2 < 2; ks2++) {
      bf16x8 af[4], bf[4];
#pragma unroll
      for (int mi = 0; mi < 4; mi++) {
        const int row = wm + mi * 16 + lm;
        af[mi] = *reinterpret_cast<const bf16x8*>(
            &Ac[row * 64 + (((ks2 * 4 + quad) ^ (row & 7)) * 8)]);
      }
#pragma unroll
      for (int ni = 0; ni < 4; ni++) {
        const int row = wn + ni * 16 + lm;
        bf[ni] = *reinterpret_cast<const bf16x8*>(
            &Bc[row * 64 + (((ks2 * 4 + quad) ^ (row & 7)) * 8)]);
      }
#pragma unroll
      for (int mi = 0; mi < 4; mi++)
#pragma unroll
        for (int ni = 0; ni < 4; ni++)
          acc[mi][ni] = __builtin_amdgcn_mfma_f32_16x16x32_bf16(af[mi], bf[ni], acc[mi][ni], 0, 0, 0);
    }
    __builtin_amdgcn_sched_barrier(0);
    __builtin_amdgcn_s_barrier();   // all waves done reading cur before it+1 overwrites buf cur^1... and it+2 overwrites cur
  }

  // epilogue: lane l, reg r -> C[m0+wm+mi*16+quad*4+r][n0+wn+ni*16+lm]
#pragma unroll
  for (int mi = 0; mi < 4; mi++)
#pragma unroll
    for (int ni = 0; ni < 4; ni++) {
      const int n = n0 + wn + ni * 16 + lm;
      const float bvn = BROW ? 0.f : bias[n];
      const int mb = m0 + wm + mi * 16 + quad * 4;
      float v[4];
#pragma unroll
      for (int r = 0; r < 4; r++)
        v[r] = acc[mi][ni][r] + (BROW ? bias[mb + r] : bvn);
      if constexpr (sizeof(OT) == 2) {
        const u32 w01 = pk2(v[0], v[1]), w23 = pk2(v[2], v[3]);
        ((u16*)C)[(size_t)(mb + 0) * N + n] = (u16)w01;
        ((u16*)C)[(size_t)(mb + 1) * N + n] = (u16)(w01 >> 16);
        ((u16*)C)[(size_t)(mb + 2) * N + n] = (u16)w23;
        ((u16*)C)[(size_t)(mb + 3) * N + n] = (u16)(w23 >> 16);
      } else {
#pragma unroll
        for (int r = 0; r < 4; r++)
          ((float*)C)[(size_t)(mb + r) * N + n] = v[r];
      }
    }
}

// ============================================================
// rf [H][HD][F] f32 -> rft [H][F][HD] f32 (contiguous wave-uniform rows)
// ============================================================
__global__ void rf_transpose(const float* __restrict__ rf, float* __restrict__ rft)
{
  const int h = blockIdx.x, d = blockIdx.y, f = threadIdx.x;
  rft[((size_t)h * Ff + f) * HDd + d] = rf[((size_t)(h * HDd + d)) * Ff + f];
}

// ============================================================
// Fused kv/ksum via MFMA (round-6, verified).
// ============================================================
#define NSPLIT 16
#define SCHUNKS (Ss / NSPLIT / 64)   // 4 chunks of 64 rows

__global__ __launch_bounds__(256, 2) void kv_fused(
    const u16* __restrict__ Km, const u16* __restrict__ Vt,
    const float* __restrict__ rft, float* __restrict__ kv, float* __restrict__ ksum)
{
  __shared__ __align__(16) u16 KS[64 * 64];       // 8KB  K chunk [s][d] swizzled
  __shared__ __align__(16) u16 VS[64 * 64];       // 8KB  Vt chunk [d][s] swizzled
  __shared__ __align__(16) u16 PT[4][64 * 64];    // 32KB per-wave P^T [f][s] swizzled

  const int bh = blockIdx.x;
  const int b = bh >> 4, h = bh & 15;
  const int s0 = blockIdx.y * (Ss / NSPLIT);
  const int tid = threadIdx.x;
  const int wave = tid >> 6, lane = tid & 63;
  const int quad = lane >> 4, lm = lane & 15;
  const int F0 = wave * 64;

  // rf fragments in regs (stage-1 B operand): rft[h][F0+ni*16+lm][ks*32+quad*8..+8]
  bf16x8 bfr[4][2];
  {
    const float* rh = rft + (size_t)h * Ff * HDd;
#pragma unroll
    for (int ni = 0; ni < 4; ni++) {
      const float* rrow = rh + (size_t)(F0 + ni * 16 + lm) * HDd;
#pragma unroll
      for (int ks = 0; ks < 2; ks++) {
        float4 a = *reinterpret_cast<const float4*>(rrow + ks * 32 + quad * 8);
        float4 e = *reinterpret_cast<const float4*>(rrow + ks * 32 + quad * 8 + 4);
        union { u32 w[4]; bf16x8 v; } u;
        u.w[0] = pk2(a.x, a.y); u.w[1] = pk2(a.z, a.w);
        u.w[2] = pk2(e.x, e.y); u.w[3] = pk2(e.z, e.w);
        bfr[ni][ks] = u.v;
      }
    }
  }

  // staging geometry: slot j in [0,512): LDS byte j*16; r=j>>3, cs=j&7,
  // source col c = cs ^ (r&7) (involution: swizzled reads recover c=ks*4+quad).
  const int j0 = wave * 64 + lane, j1 = j0 + 256;
  const int r0 = j0 >> 3, c0 = (j0 & 7) ^ (r0 & 7);
  const int r1 = j1 >> 3, c1 = (j1 & 7) ^ (r1 & 7);

  f32x4 kvacc[4][4] = {};
  float kss[4] = {0.f, 0.f, 0.f, 0.f};

#pragma unroll 1
  for (int ch = 0; ch < SCHUNKS; ch++) {
    const int sc = s0 + ch * 64;
    gload_lds16(Km + (size_t)(b * Ss + sc + r0) * Dd + h * 64 + c0 * 8, &KS[(wave * 64) * 8]);
    gload_lds16(Km + (size_t)(b * Ss + sc + r1) * Dd + h * 64 + c1 * 8, &KS[(wave * 64 + 256) * 8]);
    gload_lds16(Vt + (size_t)(h * 64 + r0) * Mm + b * Ss + sc + c0 * 8, &VS[(wave * 64) * 8]);
    gload_lds16(Vt + (size_t)(h * 64 + r1) * Mm + b * Ss + sc + c1 * 8, &VS[(wave * 64 + 256) * 8]);
    __syncthreads();   // drains vmcnt: staged data visible to all waves

    // stage 1 per-mi: P[s-block mi][f F0..F0+63] = K @ rf^T; pmi live only here
#pragma unroll
    for (int mi = 0; mi < 4; mi++) {
      const int row = mi * 16 + lm;                  // s row
      f32x4 pmi[4] = {};
#pragma unroll
      for (int ks2 = 0; ks2 < 2; ks2++) {
        bf16x8 af = *reinterpret_cast<const bf16x8*>(
            (const char*)KS + row * 128 + (((ks2 * 4 + quad) ^ (row & 7)) * 16));
#pragma unroll
        for (int ni = 0; ni < 4; ni++)
          pmi[ni] = __builtin_amdgcn_mfma_f32_16x16x32_bf16(af, bfr[ni][ks2], pmi[ni], 0, 0, 0);
      }
      // softplus + ksum partials + write P^T bf16 into this wave's PT slice
#pragma unroll
      for (int ni = 0; ni < 4; ni++) {
        float v0 = sfast(pmi[ni][0]);
        float v1 = sfast(pmi[ni][1]);
        float v2 = sfast(pmi[ni][2]);
        float v3 = sfast(pmi[ni][3]);
        kss[ni] += (v0 + v1) + (v2 + v3);
        int frow = ni * 16 + lm;                     // f row; s cols = mi*16+quad*4+rr
        int off = (frow * 128 + mi * 32 + quad * 8) ^ ((frow & 7) << 4);
        *reinterpret_cast<uint2*>((char*)&PT[wave][0] + off) =
            make_uint2(pk2(v0, v1), pk2(v2, v3));
      }
    }

    // stage 2: kv[f][d] += P^T @ Vt (own PT + shared VS; 2 k-steps)
#pragma unroll
    for (int ks2 = 0; ks2 < 2; ks2++) {
      bf16x8 a2[4], b2[4];
#pragma unroll
      for (int mi = 0; mi < 4; mi++) {
        int row = mi * 16 + lm;                      // f row
        a2[mi] = *reinterpret_cast<const bf16x8*>(
            (char*)&PT[wave][0] + row * 128 + (((ks2 * 4 + quad) ^ (row & 7)) * 16));
      }
#pragma unroll
      for (int ni = 0; ni < 4; ni++) {
        int row = ni * 16 + lm;                      // d row
        b2[ni] = *reinterpret_cast<const bf16x8*>(
            (const char*)VS + row * 128 + (((ks2 * 4 + quad) ^ (row & 7)) * 16));
      }
#pragma unroll
      for (int mi = 0; mi < 4; mi++)
#pragma unroll
        for (int ni = 0; ni < 4; ni++)
          kvacc[mi][ni] = __builtin_amdgcn_mfma_f32_16x16x32_bf16(a2[mi], b2[ni], kvacc[mi][ni], 0, 0, 0);
    }
    __syncthreads();   // all waves done with KS/VS before next chunk overwrites
  }

  // epilogue: f32 atomics into kv[bh][f][d] and ksum[bh][f]
  float* kvp = kv + (size_t)bh * Ff * HDd;
#pragma unroll
  for (int mi = 0; mi < 4; mi++)
#pragma unroll
    for (int ni = 0; ni < 4; ni++)
#pragma unroll
      for (int rr2 = 0; rr2 < 4; rr2++) {
        int f = F0 + mi * 16 + quad * 4 + rr2;
        int d = ni * 16 + lm;
        atomicAdd(kvp + (size_t)f * HDd + d, kvacc[mi][ni][rr2]);
      }
#pragma unroll
  for (int ni = 0; ni < 4; ni++) {
    float v = kss[ni];
    v += __shfl_xor(v, 16, 64);
    v += __shfl_xor(v, 32, 64);
    if (quad == 0) atomicAdd(ksum + (size_t)bh * Ff + F0 + ni * 16 + lm, v);
  }
}

// ============================================================
// kv f32 [bh][f=256][d=64] -> kvT bf16 [bh][d=64][f=256]
// ============================================================
__global__ void kvt_cvt(const float* __restrict__ kv, u16* __restrict__ kvtb)
{
  const int bh = blockIdx.x;
  const int d = threadIdx.x & 63, fg = threadIdx.x >> 6;
  const float* src = kv + (size_t)bh * Ff * HDd + d;
  u32* dst = reinterpret_cast<u32*>(kvtb + (size_t)bh * HDd * Ff + (size_t)d * Ff + fg * 64);
#pragma unroll
  for (int j = 0; j < 32; j++) {
    float v0 = src[(size_t)(fg * 64 + 2 * j) * HDd];
    float v1 = src[(size_t)(fg * 64 + 2 * j + 1) * HDd];
    dst[j] = pk2(v0, v1);
  }
}

// ============================================================
// Fused attention via MFMA. Round-8: per-mi stage-1 (kv-r6 anti-reg
// pattern): pmi[4] (16 regs) replaces p[4][4] (64); Q frags loaded per-mi
// (8 vs 32). Per-(mi,ni) MFMA order unchanged (ks0->ks1) -> bit-identical.
// Live-set drop should lift residency 2 -> 3-4 blocks/CU (this kernel is
// latency-bound: VALUBusy 56%, MfmaUtil 7%, HBM 7%).
// ============================================================
#define ASPLIT 16
#define ACHUNKS (Ss / ASPLIT / 64)   // 4 chunks of 64 rows

__global__ __launch_bounds__(256, 2) void attn_fused(
    const u16* __restrict__ Qm, const float* __restrict__ rft,
    const u16* __restrict__ kvtb, const float* __restrict__ ksum,
    u16* __restrict__ attnb)
{
  __shared__ __align__(16) u16 P4[4][64 * 64];    // 32KB [fb][s][f'] swizzled
  __shared__ __align__(16) float den4[64][4];     // [s][wave] partial denominators

  const int bh = blockIdx.x;
  const int b = bh >> 4, h = bh & 15;
  const int s0 = blockIdx.y * (Ss / ASPLIT);
  const int tid = threadIdx.x;
  const int wave = tid >> 6, lane = tid & 63;
  const int quad = lane >> 4, lm = lane & 15;
  const int F0 = wave * 64;

  // rf fragments (stage-1 B operand): rft[h][F0+ni*16+lm][ks*32+quad*8 ..+8]
  bf16x8 bfr[4][2];
  {
    const float* rh = rft + (size_t)h * Ff * HDd;
#pragma unroll
    for (int ni = 0; ni < 4; ni++) {
      const float* rrow = rh + (size_t)(F0 + ni * 16 + lm) * HDd;
#pragma unroll
      for (int ks = 0; ks < 2; ks++) {
        float4 a = *reinterpret_cast<const float4*>(rrow + ks * 32 + quad * 8);
        float4 e = *reinterpret_cast<const float4*>(rrow + ks * 32 + quad * 8 + 4);
        union { u32 w[4]; bf16x8 v; } u;
        u.w[0] = pk2(a.x, a.y); u.w[1] = pk2(a.z, a.w);
        u.w[2] = pk2(e.x, e.y); u.w[3] = pk2(e.z, e.w);
        bfr[ni][ks] = u.v;
      }
    }
  }
  // kvT fragments (stage-2 B operand): kvtb[bh][wave*16+lm][fb*64+k2*32+quad*8 ..+8]
  bf16x8 b2r[4][2];
  {
    const u16* kb = kvtb + (size_t)bh * HDd * Ff + (size_t)(wave * 16 + lm) * Ff;
#pragma unroll
    for (int fb = 0; fb < 4; fb++)
#pragma unroll
      for (int k2 = 0; k2 < 2; k2++)
        b2r[fb][k2] = *reinterpret_cast<const bf16x8*>(kb + fb * 64 + k2 * 32 + quad * 8);
  }
  // ksum per lane (f = F0 + ni*16 + lm)
  float ksv[4];
#pragma unroll
  for (int ni = 0; ni < 4; ni++)
    ksv[ni] = ksum[(size_t)bh * Ff + F0 + ni * 16 + lm];

  // chunk-invariant P4 write offsets (row = mi*16 + quad*4 + {ra,rb}; mi*16 ≡ 0
  // mod 8 so the XOR term is mi-independent; mi contributes +mi*2048 bytes)
  const int odd = lm & 1;
  u32 pOffA[4], pOffB[4];
  char* const ptb = (char*)&P4[wave][0];
  {
    const int ra = quad * 4 + (odd ? 2 : 0);
    const int rb = quad * 4 + (odd ? 3 : 1);
#pragma unroll
    for (int ni = 0; ni < 4; ni++) {
      const int fpb = ni * 16 + (lm & ~1);
      const int cc = fpb >> 3, bib = (fpb & 7) * 2;
      pOffA[ni] = ra * 128 + ((cc ^ (ra & 7)) << 4) + bib;
      pOffB[ni] = rb * 128 + ((cc ^ (rb & 7)) << 4) + bib;
    }
  }

  for (int ch = 0; ch < ACHUNKS; ch++) {
    const int sc0 = s0 + ch * 64;

    // stage 1 per-mi: Q frags direct from global, MFMA, softplus, pack, den
#pragma unroll
    for (int mi = 0; mi < 4; mi++) {
      const u16* qrow = Qm + (size_t)(b * Ss + sc0 + mi * 16 + lm) * Dd + h * 64;
      const bf16x8 a0 = *reinterpret_cast<const bf16x8*>(qrow + quad * 8);
      const bf16x8 a1 = *reinterpret_cast<const bf16x8*>(qrow + 32 + quad * 8);
      f32x4 pmi[4] = {};
#pragma unroll
      for (int ni = 0; ni < 4; ni++)
        pmi[ni] = __builtin_amdgcn_mfma_f32_16x16x32_bf16(a0, bfr[ni][0], pmi[ni], 0, 0, 0);
#pragma unroll
      for (int ni = 0; ni < 4; ni++)
        pmi[ni] = __builtin_amdgcn_mfma_f32_16x16x32_bf16(a1, bfr[ni][1], pmi[ni], 0, 0, 0);

      const int sbase = mi * 16 + quad * 4;
      float dd[4] = {0.f, 0.f, 0.f, 0.f};
#pragma unroll
      for (int ni = 0; ni < 4; ni++) {
        u32 pk01 = pk2(sfast(pmi[ni][0]), sfast(pmi[ni][1]));
        u32 pk23 = pk2(sfast(pmi[ni][2]), sfast(pmi[ni][3]));
        dd[0] += bflo(pk01) * ksv[ni];
        dd[1] += bfhi(pk01) * ksv[ni];
        dd[2] += bflo(pk23) * ksv[ni];
        dd[3] += bfhi(pk23) * ksv[ni];
        u32 ob01 = (u32)__shfl_xor((int)pk01, 1, 64);
        u32 ob23 = (u32)__shfl_xor((int)pk23, 1, 64);
        // even lane: (pk01, ob01); odd lane: (ob23, pk23) — then 2 v_perm_b32
        u32 s0v = odd ? ob23 : pk01;
        u32 s1v = odd ? pk23 : ob01;
        u32 w_a = __builtin_amdgcn_perm(s1v, s0v, 0x05040100u);   // lo16(s0)|lo16(s1)<<16
        u32 w_b = __builtin_amdgcn_perm(s1v, s0v, 0x07060302u);   // hi16(s0)|hi16(s1)<<16
        *reinterpret_cast<u32*>(ptb + pOffA[ni] + mi * 2048) = w_a;
        *reinterpret_cast<u32*>(ptb + pOffB[ni] + mi * 2048) = w_b;
      }
      // reduce den partials over lm (16-lane groups), write per-wave partial
#pragma unroll
      for (int r = 0; r < 4; r++) {
        float v = dd[r];
        v += __shfl_xor(v, 1, 64);
        v += __shfl_xor(v, 2, 64);
        v += __shfl_xor(v, 4, 64);
        v += __shfl_xor(v, 8, 64);
        if (lm == 0) den4[sbase + r][wave] = v;
      }
    }
    __syncthreads();   // P4 + den4 complete

    // stage 2: attn[s][d] = P @ kvT, waves split by 16-wide d-slices
    f32x4 acc2[4] = {};
#pragma unroll
    for (int fb = 0; fb < 4; fb++)
#pragma unroll
      for (int k2 = 0; k2 < 2; k2++) {
        bf16x8 af2[4];
#pragma unroll
        for (int mi = 0; mi < 4; mi++) {
          int row = mi * 16 + lm;                  // s row
          af2[mi] = *reinterpret_cast<const bf16x8*>(
              (char*)&P4[fb][0] + row * 128 + (((k2 * 4 + quad) ^ (row & 7)) << 4));
        }
#pragma unroll
        for (int mi = 0; mi < 4; mi++)
          acc2[mi] = __builtin_amdgcn_mfma_f32_16x16x32_bf16(af2[mi], b2r[fb][k2], acc2[mi], 0, 0, 0);
      }

    // divide by den, pk2-pair cvt, bf16 store: out[s=mi*16+quad*4+r][d=wave*16+lm]
#pragma unroll
    for (int mi = 0; mi < 4; mi++) {
      float o[4];
#pragma unroll
      for (int r = 0; r < 4; r++) {
        const int s = mi * 16 + quad * 4 + r;
        float4 dv = *reinterpret_cast<const float4*>(&den4[s][0]);
        const float inv = 1.f / ((dv.x + dv.y) + (dv.z + dv.w) + 1e-8f);
        o[r] = acc2[mi][r] * inv;
      }
      const u32 w01 = pk2(o[0], o[1]), w23 = pk2(o[2], o[3]);
      const size_t ob = (size_t)(b * Ss + sc0 + mi * 16 + quad * 4) * Dd + h * 64 + wave * 16 + lm;
      attnb[ob]          = (u16)w01;
      attnb[ob + Dd]     = (u16)(w01 >> 16);
      attnb[ob + 2 * Dd] = (u16)w23;
      attnb[ob + 3 * Dd] = (u16)(w23 >> 16);
    }
    __syncthreads();   // before next chunk overwrites P4/den4
  }
}

// ============================================================
extern "C" void kernel_launch(void* const* d_in, const int* in_sizes, int n_in,
                              void* d_out, int out_size, void* d_ws, size_t ws_size,
                              hipStream_t stream)
{
  const float* x  = (const float*)d_in[0];
  const float* Wq = (const float*)d_in[1];
  const float* bq = (const float*)d_in[2];
  const float* Wk = (const float*)d_in[3];
  const float* bk = (const float*)d_in[4];
  const float* Wv = (const float*)d_in[5];
  const float* bv = (const float*)d_in[6];
  const float* Wo = (const float*)d_in[7];
  const float* bo = (const float*)d_in[8];
  const float* rf = (const float*)d_in[9];

  // workspace (~147 MB). attn-bf16 ALIASES xb (dead after V^T GEMM);
  // kvT-bf16 ALIASES wqb (dead after Q GEMM).
  char* w = (char*)d_ws;
  u16* xb = (u16*)w;        w += (size_t)Mm * Dd * 2;               // 33.5 MB (also attn-bf16)
  u16* q  = (u16*)w;        w += (size_t)Mm * Dd * 2;               // 33.5 MB
  u16* k  = (u16*)w;        w += (size_t)Mm * Dd * 2;               // 33.5 MB
  u16* vt = (u16*)w;        w += (size_t)Mm * Dd * 2;               // 33.5 MB  V^T [1024][16384]
  u16* wqb = (u16*)w;       w += (size_t)Dd * Dd * 2;               // 2 MB (also kvT bf16)
  u16* wkb = (u16*)w;       w += (size_t)Dd * Dd * 2;
  u16* wvb = (u16*)w;       w += (size_t)Dd * Dd * 2;
  u16* wob = (u16*)w;       w += (size_t)Dd * Dd * 2;
  float* kv = (float*)w;    w += (size_t)(Bb * Hh) * Ff * HDd * 4;  // 4.19 MB
  float* ks = (float*)w;    w += (size_t)(Bb * Hh) * Ff * 4;        // 64 KB
  float* rft = (float*)w;   w += (size_t)Hh * Ff * HDd * 4;         // 1.05 MB
  u16* kvtb = wqb;          // 2 MB alias: kvT bf16 [bh][d][f]

  // f32 -> bf16 conversions (weights merged into one launch; dsts contiguous)
  cvt_bf16<<<(Mm * Dd / 8 + 255) / 256, 256, 0, stream>>>(x, xb, Mm * Dd);
  cvt_w4<<<dim3(Dd * Dd / 8 / 256, 4), 256, 0, stream>>>(Wq, Wk, Wv, Wo, wqb);

  const int nz = (Bb * Hh) * Ff * HDd + (Bb * Hh) * Ff;
  zero_f32<<<(nz + 255) / 256, 256, 0, stream>>>(kv, nz);
  rf_transpose<<<dim3(Hh, HDd), 256, 0, stream>>>(rf, rft);

  const dim3 gg(Mm / 128, Dd / 128);
  mfma_gemm_bt<u16, false><<<gg, 256, 0, stream>>>(xb, wqb, bq, q, Mm, Dd, Dd);
  mfma_gemm_bt<u16, false><<<gg, 256, 0, stream>>>(xb, wkb, bk, k, Mm, Dd, Dd);
  // V^T directly: C[d][m] = sum_k Wv[d][k] x[m][k] + bv[d]  (bias per-row)
  const dim3 gv(Dd / 128, Mm / 128);
  mfma_gemm_bt<u16, true><<<gv, 256, 0, stream>>>(wvb, xb, bv, vt, Dd, Mm, Dd);

  // fused MFMA kv/ksum
  kv_fused<<<dim3(Bb * Hh, NSPLIT), 256, 0, stream>>>(k, vt, rft, kv, ks);

  // kv -> kvT bf16 (into dead wqb region)
  kvt_cvt<<<Bb * Hh, 256, 0, stream>>>(kv, kvtb);

  // fused MFMA attention (writes bf16 into dead xb region)
  attn_fused<<<dim3(Bb * Hh, ASPLIT), 256, 0, stream>>>(q, rft, kvtb, ks, xb);

  // final projection: f32 output
  mfma_gemm_bt<float, false><<<gg, 256, 0, stream>>>(xb, wob, bo, (float*)d_out, Mm, Dd, Dd);
}